// Round 1
// baseline (1202.088 us; speedup 1.0000x reference)
//
#include <hip/hip_runtime.h>
#include <math.h>

#define NN 100000
#define EE 1600000

typedef __attribute__((ext_vector_type(8))) short bf16x8;
typedef __attribute__((ext_vector_type(4))) float f32x4;

__device__ __forceinline__ unsigned short f2bf(float x){
  union { float f; unsigned u; } v; v.f = x;
  unsigned r = v.u + 0x7FFFu + ((v.u >> 16) & 1u);
  return (unsigned short)(r >> 16);
}
__device__ __forceinline__ float bf2f(unsigned short h){
  union { unsigned u; float f; } v; v.u = ((unsigned)h) << 16; return v.f;
}
__device__ __forceinline__ float sigm(float x){ return 1.0f/(1.0f+expf(-x)); }

// ---------------- degree / CSR build ----------------
__global__ __launch_bounds__(256) void k_deg(const int* __restrict__ src, const int* __restrict__ dst,
                      int* __restrict__ dout, int* __restrict__ din){
  int e = blockIdx.x*256 + threadIdx.x;
  if (e < EE){ atomicAdd(&dout[src[e]],1); atomicAdd(&din[dst[e]],1); }
}

__global__ __launch_bounds__(256) void k_norm(const int* __restrict__ dout, const int* __restrict__ din,
                       float* __restrict__ ns, float* __restrict__ nd){
  int n = blockIdx.x*256+threadIdx.x;
  if (n < NN){
    ns[n] = rsqrtf((float)max(dout[n],1));
    nd[n] = rsqrtf((float)max(din[n],1));
  }
}

__global__ __launch_bounds__(256) void k_inv(const int* __restrict__ perm, int* __restrict__ inv){
  int n = blockIdx.x*256+threadIdx.x;
  if (n<NN) inv[perm[n]] = n;
}

// single-block exclusive/inclusive scan of deg_in -> row_ptr, cursor
__global__ __launch_bounds__(1024) void k_scan(const int* __restrict__ din, int* __restrict__ row_ptr,
                       int* __restrict__ cursor){
  __shared__ int wsum[16];
  __shared__ int carry;
  int t = threadIdx.x;
  int lane = t & 63, w = t >> 6;
  if (t==0){ carry = 0; row_ptr[0] = 0; }
  __syncthreads();
  for (int base=0; base<NN; base+=1024){
    int i = base+t;
    int v = (i<NN)? din[i] : 0;
    // wave-inclusive scan
    int x = v;
    #pragma unroll
    for (int off=1; off<64; off<<=1){
      int y = __shfl_up(x, off);
      if (lane>=off) x += y;
    }
    if (lane==63) wsum[w] = x;
    __syncthreads();
    int pre = carry;
    for (int j=0;j<w;j++) pre += wsum[j];
    int incl = x + pre;
    if (i<NN){ row_ptr[i+1] = incl; cursor[i] = incl - v; }
    __syncthreads();
    if (t==1023) carry = incl;
    __syncthreads();
  }
}

__global__ __launch_bounds__(256) void k_fill(const int* __restrict__ src, const int* __restrict__ dst,
                       int* __restrict__ cursor, int* __restrict__ col){
  int e = blockIdx.x*256+threadIdx.x;
  if (e<EE){ int pos = atomicAdd(&cursor[dst[e]],1); col[pos] = src[e]; }
}

// ---------------- MFMA GEMM:  out = A(N x KDIM) @ W(KDIM x 128) ----------------
// IN_MODE: 0 = plain fp32 ; 1 = sigmoid(relu(a)*rn[row])
// OUT_MODE: 0 = zs/zp special (out0[row]=v*scale[row], out1[inv[row]]=v*scale[inv[row]])
//           1 = out0[row] = v*scale[row]  (bf16)
//           2 = out0[row] = v             (bf16)
// WTRANS: false: W is KDIM x 128 row-major;  true: W is 128 x KDIM row-major (use W^T)
template<int KDIM, int IN_MODE, int OUT_MODE, bool WTRANS>
__global__ __launch_bounds__(256) void k_gemm(
    const float* __restrict__ A, const float* __restrict__ W,
    unsigned short* __restrict__ out0, unsigned short* __restrict__ out1,
    const float* __restrict__ scale, const int* __restrict__ inv,
    const float* __restrict__ rn)
{
  constexpr int BM=64, BN=128, BK=32, SA=40, SB=40;
  __shared__ __align__(16) unsigned short Asm[BM*SA];
  __shared__ __align__(16) unsigned short Bsm[BN*SB];
  int row0 = blockIdx.x * BM;
  int t = threadIdx.x;
  int wave = t >> 6, lane = t & 63;
  f32x4 acc[8] = {};

  for (int k0 = 0; k0 < KDIM; k0 += BK) {
    __syncthreads();
    // stage A tile: 64 rows x 32 cols (fp32 -> bf16)
    {
      int r = t >> 2;
      int q = t & 3;
      int row = row0 + r;
      float vals[8];
      if (row < NN) {
        const float* p = A + (size_t)row * KDIM + k0 + q*8;
        float4 a = *(const float4*)p;
        float4 b = *(const float4*)(p+4);
        vals[0]=a.x; vals[1]=a.y; vals[2]=a.z; vals[3]=a.w;
        vals[4]=b.x; vals[5]=b.y; vals[6]=b.z; vals[7]=b.w;
        if constexpr (IN_MODE==1){
          float r_ = rn[row];
          #pragma unroll
          for (int i=0;i<8;i++) vals[i] = sigm(fmaxf(vals[i],0.0f)*r_);
        }
      } else {
        #pragma unroll
        for (int i=0;i<8;i++) vals[i]=0.0f;
      }
      unsigned short* dstp = &Asm[r*SA + q*8];
      #pragma unroll
      for (int i=0;i<8;i++) dstp[i] = f2bf(vals[i]);
    }
    // stage B tile transposed: Bsm[col*SB + kk]
    if constexpr (!WTRANS) {
      int kr = t >> 3;
      int c0 = (t & 7) * 16;
      const float* p = W + (size_t)(k0+kr)*BN + c0;
      #pragma unroll
      for (int j=0;j<16;j++) Bsm[(c0+j)*SB + kr] = f2bf(p[j]);
    } else {
      int d = t >> 1;
      int kk0 = (t & 1) * 16;
      const float* p = W + (size_t)d*KDIM + k0 + kk0;
      #pragma unroll
      for (int j=0;j<16;j++) Bsm[d*SB + kk0 + j] = f2bf(p[j]);
    }
    __syncthreads();
    // fragments + MFMA (A,B use the same k-bijection -> layout-robust)
    int arow = wave*16 + (lane & 15);
    int kof = (lane >> 4) * 8;
    bf16x8 a = *(const bf16x8*)&Asm[arow*SA + kof];
    #pragma unroll
    for (int j=0;j<8;j++){
      bf16x8 b = *(const bf16x8*)&Bsm[(j*16 + (lane & 15))*SB + kof];
      acc[j] = __builtin_amdgcn_mfma_f32_16x16x32_bf16(a, b, acc[j], 0, 0, 0);
    }
  }
  // epilogue: C/D layout col=lane&15, row=(lane>>4)*4+reg
  int rbase = row0 + wave*16 + (lane>>4)*4;
  int c = lane & 15;
  #pragma unroll
  for (int j=0;j<8;j++){
    int col = j*16 + c;
    #pragma unroll
    for (int r=0;r<4;r++){
      int row = rbase + r;
      if (row < NN) {
        float v = acc[j][r];
        if constexpr (OUT_MODE==0){
          out0[(size_t)row*128 + col] = f2bf(v * scale[row]);
          int ir = inv[row];
          out1[(size_t)ir*128 + col] = f2bf(v * scale[ir]);
        } else if constexpr (OUT_MODE==1){
          out0[(size_t)row*128 + col] = f2bf(v * scale[row]);
        } else {
          out0[(size_t)row*128 + col] = f2bf(v);
        }
      }
    }
  }
}

// ---------------- CSR aggregation, width 128, two value arrays ----------------
template<bool RESID>
__global__ __launch_bounds__(256) void k_agg128(
  const unsigned short* __restrict__ va, const unsigned short* __restrict__ vb,
  const int* __restrict__ row_ptr, const int* __restrict__ col,
  const float* __restrict__ nd, const float* __restrict__ bias,
  float* __restrict__ oa, float* __restrict__ ob)
{
  int wave = threadIdx.x >> 6, lane = threadIdx.x & 63;
  int row = blockIdx.x * 4 + wave;
  if (row >= NN) return;
  int s = row_ptr[row], e = row_ptr[row+1];
  float a0=0.f,a1=0.f,b0=0.f,b1=0.f;
  size_t loff = (size_t)lane*2;
  for (int i=s;i<e;i++){
    int sc = col[i];
    unsigned ua = *(const unsigned*)(va + (size_t)sc*128 + loff);
    unsigned ub = *(const unsigned*)(vb + (size_t)sc*128 + loff);
    a0 += bf2f((unsigned short)ua);  a1 += bf2f((unsigned short)(ua>>16));
    b0 += bf2f((unsigned short)ub);  b1 += bf2f((unsigned short)(ub>>16));
  }
  float ndr = nd[row];
  int c0 = lane*2;
  size_t o = (size_t)row*128 + c0;
  float r0 = a0*ndr + bias[c0];
  float r1 = a1*ndr + bias[c0+1];
  float s0 = b0*ndr + bias[c0];
  float s1 = b1*ndr + bias[c0+1];
  if constexpr (RESID){ r0 += oa[o]; r1 += oa[o+1]; s0 += ob[o]; s1 += ob[o+1]; }
  oa[o]=r0; oa[o+1]=r1;
  ob[o]=s0; ob[o+1]=s1;
}

// width-16 aggregation (GC3) -> h (fp32 out)
__global__ __launch_bounds__(256) void k_agg16(
  const unsigned short* __restrict__ va, const unsigned short* __restrict__ vb,
  const int* __restrict__ row_ptr, const int* __restrict__ col,
  const float* __restrict__ nd, const float* __restrict__ b3,
  float* __restrict__ hout, float* __restrict__ h2)
{
  int t = threadIdx.x;
  int row = blockIdx.x*16 + (t>>4);
  int c = t & 15;
  if (row >= NN) return;
  int s = row_ptr[row], e = row_ptr[row+1];
  float aa=0.f, ab=0.f;
  for (int i=s;i<e;i++){
    int sc = col[i];
    aa += bf2f(va[(size_t)sc*16 + c]);
    ab += bf2f(vb[(size_t)sc*16 + c]);
  }
  float ndr = nd[row]; float bb = b3[c];
  hout[(size_t)row*16+c] = aa*ndr + bb;
  h2  [(size_t)row*16+c] = ab*ndr + bb;
}

// ---------------- GC3 mult: th = (o @ W3) * ns[row]  (128 -> 16) ----------------
__global__ __launch_bounds__(256) void k_gemm3(const float* __restrict__ o, const float* __restrict__ W3,
     const float* __restrict__ ns, unsigned short* __restrict__ th)
{
  __shared__ float Ws[128*16];
  int t = threadIdx.x;
  for (int i=t;i<2048;i+=256) Ws[i]=W3[i];
  __syncthreads();
  int row = blockIdx.x*16 + (t>>4);
  int c = t & 15;
  if (row >= NN) return;
  const float* p = o + (size_t)row*128;
  float acc=0.f;
  #pragma unroll 4
  for (int k4=0;k4<32;k4++){
    float4 v = *(const float4*)(p + k4*4);
    acc += v.x*Ws[(k4*4+0)*16+c] + v.y*Ws[(k4*4+1)*16+c]
         + v.z*Ws[(k4*4+2)*16+c] + v.w*Ws[(k4*4+3)*16+c];
  }
  th[(size_t)row*16+c] = f2bf(acc*ns[row]);
}

// ---------------- reciprocal l2 norm of relu(row) ----------------
__global__ __launch_bounds__(256) void k_rnorm(const float* __restrict__ o, float* __restrict__ rn){
  int wave = threadIdx.x>>6, lane = threadIdx.x&63;
  int row = blockIdx.x*4+wave;
  if (row>=NN) return;
  const float* p = o + (size_t)row*128 + lane*2;
  float x0 = fmaxf(p[0],0.f), x1 = fmaxf(p[1],0.f);
  float s = x0*x0 + x1*x1;
  #pragma unroll
  for (int off=32; off>0; off>>=1) s += __shfl_down(s, off);
  if (lane==0) rn[row] = 1.0f / fmaxf(sqrtf(s), 1e-12f);
}

// ---------------- ret_o / ret_oa ----------------
__global__ __launch_bounds__(256) void k_ret_o(const float* __restrict__ o1, const float* __restrict__ o2,
  const unsigned short* __restrict__ v1, const unsigned short* __restrict__ v2,
  const float* __restrict__ bdo, float* __restrict__ ro, float* __restrict__ roa)
{
  int wave = threadIdx.x>>6, lane = threadIdx.x&63;
  int row = blockIdx.x*4+wave;
  if (row>=NN) return;
  size_t base = (size_t)row*128 + lane*2;
  float e0a = fmaxf(o1[base],0.f),  e0b = fmaxf(o1[base+1],0.f);
  float e1a = fmaxf(o2[base],0.f),  e1b = fmaxf(o2[base+1],0.f);
  unsigned u1 = *(const unsigned*)(v1+base);
  unsigned u2 = *(const unsigned*)(v2+base);
  float v1a = bf2f((unsigned short)u1), v1b = bf2f((unsigned short)(u1>>16));
  float v2a = bf2f((unsigned short)u2), v2b = bf2f((unsigned short)(u2>>16));
  float d00 = e0a*v1a + e0b*v1b;   // emb_o . v1
  float d01 = e1a*v1a + e1b*v1b;   // emb_oa . v1
  float d10 = e1a*v2a + e1b*v2b;   // emb_oa . v2
  float d11 = e0a*v2a + e0b*v2b;   // emb_o . v2
  #pragma unroll
  for (int off=32; off>0; off>>=1){
    d00 += __shfl_down(d00, off);
    d01 += __shfl_down(d01, off);
    d10 += __shfl_down(d10, off);
    d11 += __shfl_down(d11, off);
  }
  if (lane==0){
    float bb = bdo[0];
    ro [(size_t)row*2+0] = d00+bb;
    ro [(size_t)row*2+1] = d01+bb;
    roa[(size_t)row*2+0] = d10+bb;
    roa[(size_t)row*2+1] = d11+bb;
  }
}

// ---------------- ret_h / ret_ha ----------------
__global__ __launch_bounds__(256) void k_ret_h(const float* __restrict__ h1, const float* __restrict__ h2,
  const float* __restrict__ Wdh, const float* __restrict__ bdh,
  float* __restrict__ rh, float* __restrict__ rha)
{
  __shared__ float Ws[256];
  int t = threadIdx.x;
  if (t<256) Ws[t]=Wdh[t];
  __syncthreads();
  int n = blockIdx.x*256 + t;
  if (n>=NN) return;
  float e1[16], e2[16];
  float s1=0.f, s2=0.f;
  const float* p1 = h1 + (size_t)n*16;
  const float* p2 = h2 + (size_t)n*16;
  #pragma unroll
  for (int i=0;i<16;i++){
    e1[i]=fmaxf(p1[i],0.f); s1+=e1[i]*e1[i];
    e2[i]=fmaxf(p2[i],0.f); s2+=e2[i]*e2[i];
  }
  float r1 = 1.0f/fmaxf(sqrtf(s1),1e-12f);
  float r2 = 1.0f/fmaxf(sqrtf(s2),1e-12f);
  float g1[16], g2[16];
  #pragma unroll
  for (int i=0;i<16;i++){ g1[i]=sigm(e1[i]*r1); g2[i]=sigm(e2[i]*r2); }
  float q00=0.f,q01=0.f,q10=0.f,q11=0.f;
  #pragma unroll
  for (int d=0; d<16; d++){
    float vh1=0.f, vh2=0.f;
    #pragma unroll
    for (int e=0;e<16;e++){ vh1 += Ws[d*16+e]*g1[e]; vh2 += Ws[d*16+e]*g2[e]; }
    q00 += e1[d]*vh1; q01 += e2[d]*vh1;
    q10 += e2[d]*vh2; q11 += e1[d]*vh2;
  }
  float bb = bdh[0];
  rh [(size_t)n*2+0]=q00+bb; rh [(size_t)n*2+1]=q01+bb;
  rha[(size_t)n*2+0]=q10+bb; rha[(size_t)n*2+1]=q11+bb;
}

// ---------------- launch ----------------
extern "C" void kernel_launch(void* const* d_in, const int* in_sizes, int n_in,
                              void* d_out, int out_size, void* d_ws, size_t ws_size,
                              hipStream_t stream){
  const float* x   = (const float*)d_in[0];
  const float* W1  = (const float*)d_in[1];
  const float* b1  = (const float*)d_in[2];
  const float* W2  = (const float*)d_in[3];
  const float* b2  = (const float*)d_in[4];
  const float* W3  = (const float*)d_in[5];
  const float* b3  = (const float*)d_in[6];
  const float* Wdo = (const float*)d_in[7];
  const float* bdo = (const float*)d_in[8];
  const float* Wdh = (const float*)d_in[9];
  const float* bdh = (const float*)d_in[10];
  const int* ei    = (const int*)d_in[11];
  const int* perm  = (const int*)d_in[12];
  const int* esrc = ei;
  const int* edst = ei + EE;

  char* ws = (char*)d_ws;
  size_t off = 0;
  auto alloc = [&](size_t bytes)->void*{ void* p = ws + off; off += (bytes + 255) & ~(size_t)255; return p; };
  unsigned short* zs = (unsigned short*)alloc((size_t)NN*128*2);
  unsigned short* zp = (unsigned short*)alloc((size_t)NN*128*2);
  float* o1 = (float*)alloc((size_t)NN*128*4);
  float* o2 = (float*)alloc((size_t)NN*128*4);
  unsigned short* th1 = (unsigned short*)alloc((size_t)NN*16*2);
  unsigned short* th2 = (unsigned short*)alloc((size_t)NN*16*2);
  float* h2 = (float*)alloc((size_t)NN*16*4);
  int* deg = (int*)alloc((size_t)2*NN*4);
  int* dout_ = deg; int* din_ = deg + NN;
  float* ns = (float*)alloc((size_t)NN*4);
  float* nd = (float*)alloc((size_t)NN*4);
  int* inv  = (int*)alloc((size_t)NN*4);
  float* rn1 = (float*)alloc((size_t)NN*4);
  float* rn2 = (float*)alloc((size_t)NN*4);
  int* cursor = (int*)alloc((size_t)NN*4);
  int* row_ptr = (int*)alloc((size_t)(NN+1)*4);
  int* colx = (int*)alloc((size_t)EE*4);
  // aliases (lifetimes disjoint): t1/t2 then v1/v2 reuse zs/zp
  unsigned short* t1 = zs; unsigned short* t2 = zp;
  unsigned short* v1 = zs; unsigned short* v2 = zp;

  float* out_h   = (float*)d_out;
  float* out_ro  = out_h  + (size_t)NN*16;
  float* out_rh  = out_ro + (size_t)NN*2;
  float* out_roa = out_rh + (size_t)NN*2;
  float* out_rha = out_roa+ (size_t)NN*2;

  hipMemsetAsync(deg, 0, (size_t)2*NN*4, stream);
  k_deg <<<EE/256, 256, 0, stream>>>(esrc, edst, dout_, din_);
  k_norm<<<(NN+255)/256, 256, 0, stream>>>(dout_, din_, ns, nd);
  k_scan<<<1, 1024, 0, stream>>>(din_, row_ptr, cursor);
  k_fill<<<EE/256, 256, 0, stream>>>(esrc, edst, cursor, colx);
  k_inv <<<(NN+255)/256, 256, 0, stream>>>(perm, inv);

  int gb = (NN + 63)/64;
  // GC1: z=x@W1 once; epilogue writes zs and zp (scatter by inv-perm)
  k_gemm<1024,0,0,false><<<gb,256,0,stream>>>(x, W1, zs, zp, ns, inv, nullptr);
  k_agg128<false><<<(NN+3)/4,256,0,stream>>>(zs, zp, row_ptr, colx, nd, b1, o1, o2);
  // GC2 (+residual)
  k_gemm<128,0,1,false><<<gb,256,0,stream>>>(o1, W2, t1, nullptr, ns, nullptr, nullptr);
  k_gemm<128,0,1,false><<<gb,256,0,stream>>>(o2, W2, t2, nullptr, ns, nullptr, nullptr);
  k_agg128<true><<<(NN+3)/4,256,0,stream>>>(t1, t2, row_ptr, colx, nd, b2, o1, o2);
  // GC3
  k_gemm3<<<(NN+15)/16,256,0,stream>>>(o1, W3, ns, th1);
  k_gemm3<<<(NN+15)/16,256,0,stream>>>(o2, W3, ns, th2);
  k_agg16<<<(NN+15)/16,256,0,stream>>>(th1, th2, row_ptr, colx, nd, b3, out_h, h2);
  // discriminator (o-path)
  k_rnorm<<<(NN+3)/4,256,0,stream>>>(o1, rn1);
  k_rnorm<<<(NN+3)/4,256,0,stream>>>(o2, rn2);
  k_gemm<128,1,2,true><<<gb,256,0,stream>>>(o1, Wdo, v1, nullptr, nullptr, nullptr, rn1);
  k_gemm<128,1,2,true><<<gb,256,0,stream>>>(o2, Wdo, v2, nullptr, nullptr, nullptr, rn2);
  k_ret_o<<<(NN+3)/4,256,0,stream>>>(o1, o2, v1, v2, bdo, out_ro, out_roa);
  // discriminator (h-path)
  k_ret_h<<<(NN+255)/256,256,0,stream>>>(out_h, h2, Wdh, bdh, out_rh, out_rha);
}

// Round 2
// 934.018 us; speedup vs baseline: 1.2870x; 1.2870x over previous
//
#include <hip/hip_runtime.h>
#include <math.h>

#define NN 100000
#define EE 1600000
#define SCB 98  // ceil(NN/1024)

typedef __attribute__((ext_vector_type(8))) short bf16x8;
typedef __attribute__((ext_vector_type(4))) float f32x4;

__device__ __forceinline__ unsigned short f2bf(float x){
  union { float f; unsigned u; } v; v.f = x;
  unsigned r = v.u + 0x7FFFu + ((v.u >> 16) & 1u);
  return (unsigned short)(r >> 16);
}
__device__ __forceinline__ float bf2f(unsigned short h){
  union { unsigned u; float f; } v; v.u = ((unsigned)h) << 16; return v.f;
}
__device__ __forceinline__ float sigm(float x){ return 1.0f/(1.0f+expf(-x)); }

// ---------------- degree ----------------
__global__ __launch_bounds__(256) void k_deg(const int* __restrict__ src, const int* __restrict__ dst,
                      int* __restrict__ dout, int* __restrict__ din){
  int e = blockIdx.x*256 + threadIdx.x;
  if (e < EE){ atomicAdd(&dout[src[e]],1); atomicAdd(&din[dst[e]],1); }
}

__global__ __launch_bounds__(256) void k_norminv(const int* __restrict__ dout, const int* __restrict__ din,
                       const int* __restrict__ perm,
                       float* __restrict__ ns, float* __restrict__ nd, int* __restrict__ inv){
  int n = blockIdx.x*256+threadIdx.x;
  if (n < NN){
    ns[n] = rsqrtf((float)max(dout[n],1));
    nd[n] = rsqrtf((float)max(din[n],1));
    inv[perm[n]] = n;
  }
}

// ---------------- parallel scan (3 phases) ----------------
__global__ __launch_bounds__(1024) void k_scan1(const int* __restrict__ din, int* __restrict__ chunk,
                        int* __restrict__ bsum){
  __shared__ int wsum[16];
  int t = threadIdx.x, lane = t & 63, w = t >> 6;
  int i = blockIdx.x*1024 + t;
  int v = (i < NN) ? din[i] : 0;
  int x = v;
  #pragma unroll
  for (int off=1; off<64; off<<=1){
    int y = __shfl_up(x, off);
    if (lane>=off) x += y;
  }
  if (lane==63) wsum[w] = x;
  __syncthreads();
  int pre = 0;
  #pragma unroll
  for (int j=0;j<16;j++) if (j<w) pre += wsum[j];
  int incl = x + pre;
  if (i < NN) chunk[i] = incl;
  if (t == 1023) bsum[blockIdx.x] = incl;
}

__global__ __launch_bounds__(128) void k_scan2(const int* __restrict__ bsum, int* __restrict__ bpre,
                       int* __restrict__ row_ptr){
  __shared__ int w0tot;
  int t = threadIdx.x, lane = t & 63, w = t >> 6;
  int v = (t < SCB) ? bsum[t] : 0;
  int x = v;
  #pragma unroll
  for (int off=1; off<64; off<<=1){
    int y = __shfl_up(x, off);
    if (lane>=off) x += y;
  }
  if (w==0 && lane==63) w0tot = x;
  __syncthreads();
  int incl = x + (w ? w0tot : 0);
  if (t < SCB) bpre[t] = incl - v;
  if (t == 0) row_ptr[0] = 0;
}

__global__ __launch_bounds__(256) void k_scan3(const int* __restrict__ din, const int* __restrict__ chunk,
                       const int* __restrict__ bpre,
                       int* __restrict__ row_ptr, int* __restrict__ cursor){
  int i = blockIdx.x*256 + threadIdx.x;
  if (i < NN){
    int val = chunk[i] + bpre[i>>10];
    row_ptr[i+1] = val;
    cursor[i] = val - din[i];
  }
}

__global__ __launch_bounds__(256) void k_fill(const int* __restrict__ src, const int* __restrict__ dst,
                       int* __restrict__ cursor, int* __restrict__ col){
  int e = blockIdx.x*256+threadIdx.x;
  if (e<EE){ int pos = atomicAdd(&cursor[dst[e]],1); col[pos] = src[e]; }
}

// ---------------- weight convert: out[c*K+k] = bf16(W[k*128+c]) (trans) or bf16(W[i]) ----------------
__global__ __launch_bounds__(256) void k_wcvt(const float* __restrict__ W, unsigned short* __restrict__ out,
                       int K, int trans){
  int i = blockIdx.x*256 + threadIdx.x;
  if (i >= K*128) return;
  if (trans){
    int c = i / K, k = i - c*K;
    out[i] = f2bf(W[(size_t)k*128 + c]);
  } else {
    out[i] = f2bf(W[i]);
  }
}

// ---------------- MFMA GEMM, A direct-to-reg, B (bf16 col-major) dbuf in LDS ----------------
// IN_MODE: 0 plain ; 1 sigmoid(relu(a)*rn[row])
// OUT_MODE: 0 zs/zp scatter ; 1 out0[row]=v*scale[row%NN] ; 2 out0[row]=v
template<int KDIM, int IN_MODE, int OUT_MODE>
__global__ __launch_bounds__(256) void k_gemmA(
    const float* __restrict__ A, const unsigned short* __restrict__ Wc,
    unsigned short* __restrict__ out0, unsigned short* __restrict__ out1,
    const float* __restrict__ scale, const int* __restrict__ inv,
    const float* __restrict__ rn, int nrows)
{
  constexpr int BK=32, SB=40, NSTEP=KDIM/BK;
  __shared__ __align__(16) unsigned short Bs[2*128*SB];
  int t = threadIdx.x, wave = t>>6, lane = t&63;
  int row0 = blockIdx.x*64;
  int arow = row0 + wave*16 + (lane&15);
  int kof = (lane>>4)*8;
  int arow_c = min(arow, nrows-1);
  const float* ap = A + (size_t)arow_c*KDIM + kof;
  float rscale = 1.0f;
  if constexpr (IN_MODE==1) rscale = rn[arow_c];

  // B staging: thread t covers col=t>>1, k-offset (t&1)*16 (16 shorts = 32B)
  int sc = t>>1;
  int sk = (t&1)*16;
  const unsigned short* wp = Wc + (size_t)sc*KDIM + sk;
  unsigned short* bs0 = &Bs[0] + sc*SB + sk;

  f32x4 acc[8] = {};
  // prologue: stage buf 0
  {
    bf16x8 w0 = *(const bf16x8*)(wp);
    bf16x8 w1 = *(const bf16x8*)(wp+8);
    *(bf16x8*)(bs0) = w0;
    *(bf16x8*)(bs0+8) = w1;
  }
  __syncthreads();
  #pragma unroll
  for (int s=0; s<NSTEP; s++){
    int k0 = s*BK;
    // A fragment from global
    float av[8];
    {
      float4 a0 = *(const float4*)(ap + k0);
      float4 a1 = *(const float4*)(ap + k0 + 4);
      av[0]=a0.x; av[1]=a0.y; av[2]=a0.z; av[3]=a0.w;
      av[4]=a1.x; av[5]=a1.y; av[6]=a1.z; av[7]=a1.w;
    }
    if constexpr (IN_MODE==1){
      #pragma unroll
      for (int i=0;i<8;i++) av[i] = sigm(fmaxf(av[i],0.0f)*rscale);
    }
    bf16x8 afrag;
    #pragma unroll
    for (int i=0;i<8;i++) afrag[i] = (short)f2bf(av[i]);
    // stage next B tile into the other buffer
    if (s+1 < NSTEP){
      const unsigned short* wn = wp + k0 + BK;
      bf16x8 w0 = *(const bf16x8*)(wn);
      bf16x8 w1 = *(const bf16x8*)(wn+8);
      unsigned short* d = &Bs[0] + ((s+1)&1)*(128*SB) + sc*SB + sk;
      *(bf16x8*)(d) = w0;
      *(bf16x8*)(d+8) = w1;
    }
    // MFMA from current buffer
    const unsigned short* bb = &Bs[0] + (s&1)*(128*SB);
    #pragma unroll
    for (int j=0;j<8;j++){
      bf16x8 b = *(const bf16x8*)&bb[(j*16 + (lane&15))*SB + kof];
      acc[j] = __builtin_amdgcn_mfma_f32_16x16x32_bf16(afrag, b, acc[j], 0, 0, 0);
    }
    __syncthreads();
  }
  // epilogue: C/D layout col=lane&15, row=(lane>>4)*4+reg
  int rbase = row0 + wave*16 + (lane>>4)*4;
  int c = lane & 15;
  #pragma unroll
  for (int j=0;j<8;j++){
    int colx = j*16 + c;
    #pragma unroll
    for (int r=0;r<4;r++){
      int row = rbase + r;
      if (row < nrows){
        float v = acc[j][r];
        if constexpr (OUT_MODE==0){
          out0[(size_t)row*128 + colx] = f2bf(v * scale[row]);
          int ir = inv[row];
          out1[(size_t)ir*128 + colx] = f2bf(v * scale[ir]);
        } else if constexpr (OUT_MODE==1){
          int sidx = row >= NN ? row - NN : row;
          out0[(size_t)row*128 + colx] = f2bf(v * scale[sidx]);
        } else {
          out0[(size_t)row*128 + colx] = f2bf(v);
        }
      }
    }
  }
}

// ---------------- CSR aggregation, width 128, 16B/lane, 4 edges in flight ----------------
// RESID: adds previous oa/ob and fuses rn (= 1/max(||relu(row)||,eps)) output
template<bool RESID>
__global__ __launch_bounds__(256) void k_agg128(
  const unsigned short* __restrict__ va, const unsigned short* __restrict__ vb,
  const int* __restrict__ row_ptr, const int* __restrict__ col,
  const float* __restrict__ nd, const float* __restrict__ bias,
  float* __restrict__ oa, float* __restrict__ ob, float* __restrict__ rn)
{
  int wave = threadIdx.x >> 6, lane = threadIdx.x & 63;
  int row = blockIdx.x * 4 + wave;
  if (row >= NN) return;
  int s = row_ptr[row], e = row_ptr[row+1];
  int eg = lane >> 4;
  int c8 = (lane & 15) * 8;
  float accA[8] = {}, accB[8] = {};
  for (int i = s + eg; i < e; i += 4){
    int scn = col[i];
    bf16x8 ua = *(const bf16x8*)(va + (size_t)scn*128 + c8);
    bf16x8 ub = *(const bf16x8*)(vb + (size_t)scn*128 + c8);
    #pragma unroll
    for (int j=0;j<8;j++){
      accA[j] += bf2f((unsigned short)ua[j]);
      accB[j] += bf2f((unsigned short)ub[j]);
    }
  }
  #pragma unroll
  for (int j=0;j<8;j++){
    accA[j] += __shfl_down(accA[j], 32); accA[j] += __shfl_down(accA[j], 16);
    accB[j] += __shfl_down(accB[j], 32); accB[j] += __shfl_down(accB[j], 16);
  }
  if (lane < 16){
    float ndr = nd[row];
    size_t o = (size_t)row*128 + c8;
    float ra[8], rb[8];
    #pragma unroll
    for (int j=0;j<8;j++){
      ra[j] = accA[j]*ndr + bias[c8+j];
      rb[j] = accB[j]*ndr + bias[c8+j];
    }
    if constexpr (RESID){
      float4 p0 = *(const float4*)(oa+o);
      float4 p1 = *(const float4*)(oa+o+4);
      float4 q0 = *(const float4*)(ob+o);
      float4 q1 = *(const float4*)(ob+o+4);
      ra[0]+=p0.x; ra[1]+=p0.y; ra[2]+=p0.z; ra[3]+=p0.w;
      ra[4]+=p1.x; ra[5]+=p1.y; ra[6]+=p1.z; ra[7]+=p1.w;
      rb[0]+=q0.x; rb[1]+=q0.y; rb[2]+=q0.z; rb[3]+=q0.w;
      rb[4]+=q1.x; rb[5]+=q1.y; rb[6]+=q1.z; rb[7]+=q1.w;
    }
    float4 w0 = make_float4(ra[0],ra[1],ra[2],ra[3]);
    float4 w1 = make_float4(ra[4],ra[5],ra[6],ra[7]);
    float4 w2 = make_float4(rb[0],rb[1],rb[2],rb[3]);
    float4 w3 = make_float4(rb[4],rb[5],rb[6],rb[7]);
    *(float4*)(oa+o) = w0; *(float4*)(oa+o+4) = w1;
    *(float4*)(ob+o) = w2; *(float4*)(ob+o+4) = w3;
    if constexpr (RESID){
      float sa = 0.f, sb = 0.f;
      #pragma unroll
      for (int j=0;j<8;j++){
        float x1 = fmaxf(ra[j],0.f), x2 = fmaxf(rb[j],0.f);
        sa += x1*x1; sb += x2*x2;
      }
      #pragma unroll
      for (int off=8; off>0; off>>=1){
        sa += __shfl_down(sa, off);
        sb += __shfl_down(sb, off);
      }
      if (lane==0){
        rn[row]      = 1.0f / fmaxf(sqrtf(sa), 1e-12f);
        rn[NN + row] = 1.0f / fmaxf(sqrtf(sb), 1e-12f);
      }
    }
  }
}

// ---------------- width-16 aggregation (GC3) ----------------
__global__ __launch_bounds__(256) void k_agg16(
  const unsigned short* __restrict__ va, const unsigned short* __restrict__ vb,
  const int* __restrict__ row_ptr, const int* __restrict__ col,
  const float* __restrict__ nd, const float* __restrict__ b3,
  float* __restrict__ hout, float* __restrict__ h2)
{
  int t = threadIdx.x;
  int row = blockIdx.x*16 + (t>>4);
  int c = t & 15;
  if (row >= NN) return;
  int s = row_ptr[row], e = row_ptr[row+1];
  float aa=0.f, ab=0.f;
  for (int i=s;i<e;i++){
    int sc = col[i];
    aa += bf2f(va[(size_t)sc*16 + c]);
    ab += bf2f(vb[(size_t)sc*16 + c]);
  }
  float ndr = nd[row]; float bb = b3[c];
  hout[(size_t)row*16+c] = aa*ndr + bb;
  h2  [(size_t)row*16+c] = ab*ndr + bb;
}

// ---------------- GC3 mult (fused over 2*NN rows): th = (o @ W3) * ns[row%NN] ----------------
__global__ __launch_bounds__(256) void k_gemm3(const float* __restrict__ o, const float* __restrict__ W3,
     const float* __restrict__ ns, unsigned short* __restrict__ th, int nrows)
{
  __shared__ float Ws[128*16];
  int t = threadIdx.x;
  for (int i=t;i<2048;i+=256) Ws[i]=W3[i];
  __syncthreads();
  int row = blockIdx.x*16 + (t>>4);
  int c = t & 15;
  if (row >= nrows) return;
  const float* p = o + (size_t)row*128;
  float acc=0.f;
  #pragma unroll 4
  for (int k4=0;k4<32;k4++){
    float4 v = *(const float4*)(p + k4*4);
    acc += v.x*Ws[(k4*4+0)*16+c] + v.y*Ws[(k4*4+1)*16+c]
         + v.z*Ws[(k4*4+2)*16+c] + v.w*Ws[(k4*4+3)*16+c];
  }
  int sidx = row >= NN ? row - NN : row;
  th[(size_t)row*16+c] = f2bf(acc*ns[sidx]);
}

// ---------------- ret_o / ret_oa ----------------
__global__ __launch_bounds__(256) void k_ret_o(const float* __restrict__ o1, const float* __restrict__ o2,
  const unsigned short* __restrict__ v1, const unsigned short* __restrict__ v2,
  const float* __restrict__ bdo, float* __restrict__ ro, float* __restrict__ roa)
{
  int wave = threadIdx.x>>6, lane = threadIdx.x&63;
  int row = blockIdx.x*4+wave;
  if (row>=NN) return;
  size_t base = (size_t)row*128 + lane*2;
  float e0a = fmaxf(o1[base],0.f),  e0b = fmaxf(o1[base+1],0.f);
  float e1a = fmaxf(o2[base],0.f),  e1b = fmaxf(o2[base+1],0.f);
  unsigned u1 = *(const unsigned*)(v1+base);
  unsigned u2 = *(const unsigned*)(v2+base);
  float v1a = bf2f((unsigned short)u1), v1b = bf2f((unsigned short)(u1>>16));
  float v2a = bf2f((unsigned short)u2), v2b = bf2f((unsigned short)(u2>>16));
  float d00 = e0a*v1a + e0b*v1b;
  float d01 = e1a*v1a + e1b*v1b;
  float d10 = e1a*v2a + e1b*v2b;
  float d11 = e0a*v2a + e0b*v2b;
  #pragma unroll
  for (int off=32; off>0; off>>=1){
    d00 += __shfl_down(d00, off);
    d01 += __shfl_down(d01, off);
    d10 += __shfl_down(d10, off);
    d11 += __shfl_down(d11, off);
  }
  if (lane==0){
    float bb = bdo[0];
    ro [(size_t)row*2+0] = d00+bb;
    ro [(size_t)row*2+1] = d01+bb;
    roa[(size_t)row*2+0] = d10+bb;
    roa[(size_t)row*2+1] = d11+bb;
  }
}

// ---------------- ret_h / ret_ha ----------------
__global__ __launch_bounds__(256) void k_ret_h(const float* __restrict__ h1, const float* __restrict__ h2,
  const float* __restrict__ Wdh, const float* __restrict__ bdh,
  float* __restrict__ rh, float* __restrict__ rha)
{
  __shared__ float Ws[256];
  int t = threadIdx.x;
  if (t<256) Ws[t]=Wdh[t];
  __syncthreads();
  int n = blockIdx.x*256 + t;
  if (n>=NN) return;
  float e1[16], e2[16];
  float s1=0.f, s2=0.f;
  const float* p1 = h1 + (size_t)n*16;
  const float* p2 = h2 + (size_t)n*16;
  #pragma unroll
  for (int i=0;i<16;i++){
    e1[i]=fmaxf(p1[i],0.f); s1+=e1[i]*e1[i];
    e2[i]=fmaxf(p2[i],0.f); s2+=e2[i]*e2[i];
  }
  float r1 = 1.0f/fmaxf(sqrtf(s1),1e-12f);
  float r2 = 1.0f/fmaxf(sqrtf(s2),1e-12f);
  float g1[16], g2[16];
  #pragma unroll
  for (int i=0;i<16;i++){ g1[i]=sigm(e1[i]*r1); g2[i]=sigm(e2[i]*r2); }
  float q00=0.f,q01=0.f,q10=0.f,q11=0.f;
  #pragma unroll
  for (int d=0; d<16; d++){
    float vh1=0.f, vh2=0.f;
    #pragma unroll
    for (int e=0;e<16;e++){ vh1 += Ws[d*16+e]*g1[e]; vh2 += Ws[d*16+e]*g2[e]; }
    q00 += e1[d]*vh1; q01 += e2[d]*vh1;
    q10 += e2[d]*vh2; q11 += e1[d]*vh2;
  }
  float bb = bdh[0];
  rh [(size_t)n*2+0]=q00+bb; rh [(size_t)n*2+1]=q01+bb;
  rha[(size_t)n*2+0]=q10+bb; rha[(size_t)n*2+1]=q11+bb;
}

// ---------------- launch ----------------
extern "C" void kernel_launch(void* const* d_in, const int* in_sizes, int n_in,
                              void* d_out, int out_size, void* d_ws, size_t ws_size,
                              hipStream_t stream){
  const float* x   = (const float*)d_in[0];
  const float* W1  = (const float*)d_in[1];
  const float* b1  = (const float*)d_in[2];
  const float* W2  = (const float*)d_in[3];
  const float* b2  = (const float*)d_in[4];
  const float* W3  = (const float*)d_in[5];
  const float* b3  = (const float*)d_in[6];
  const float* Wdo = (const float*)d_in[7];
  const float* bdo = (const float*)d_in[8];
  const float* Wdh = (const float*)d_in[9];
  const float* bdh = (const float*)d_in[10];
  const int* ei    = (const int*)d_in[11];
  const int* perm  = (const int*)d_in[12];
  const int* esrc = ei;
  const int* edst = ei + EE;

  char* ws = (char*)d_ws;
  size_t off = 0;
  auto alloc = [&](size_t bytes)->void*{ void* p = ws + off; off += (bytes + 255) & ~(size_t)255; return p; };
  unsigned short* zs = (unsigned short*)alloc((size_t)NN*128*2);   // also t1 / v1
  unsigned short* zp = (unsigned short*)alloc((size_t)NN*128*2);   // also t2 / v2 (contiguous with zs)
  float* o1 = (float*)alloc((size_t)NN*128*4);
  float* o2 = (float*)alloc((size_t)NN*128*4);                    // contiguous with o1
  unsigned short* th = (unsigned short*)alloc((size_t)2*NN*16*2);
  float* h2 = (float*)alloc((size_t)NN*16*4);
  int* deg = (int*)alloc((size_t)2*NN*4);
  int* dout_ = deg; int* din_ = deg + NN;
  float* ns = (float*)alloc((size_t)NN*4);
  float* nd = (float*)alloc((size_t)NN*4);
  int* inv  = (int*)alloc((size_t)NN*4);
  float* rn = (float*)alloc((size_t)2*NN*4);
  int* cursor = (int*)alloc((size_t)NN*4);
  int* row_ptr = (int*)alloc((size_t)(NN+1)*4);
  int* colx = (int*)alloc((size_t)EE*4);
  int* chunk = (int*)alloc((size_t)NN*4);
  int* bsum = (int*)alloc((size_t)SCB*4);
  int* bpre = (int*)alloc((size_t)SCB*4);
  unsigned short* W1T = (unsigned short*)alloc((size_t)1024*128*2);
  unsigned short* W2T = (unsigned short*)alloc((size_t)128*128*2);
  unsigned short* WdoB = (unsigned short*)alloc((size_t)128*128*2);

  float* out_h   = (float*)d_out;
  float* out_ro  = out_h  + (size_t)NN*16;
  float* out_rh  = out_ro + (size_t)NN*2;
  float* out_roa = out_rh + (size_t)NN*2;
  float* out_rha = out_roa+ (size_t)NN*2;

  hipMemsetAsync(deg, 0, (size_t)2*NN*4, stream);
  // weight preconversion (independent)
  k_wcvt<<<(1024*128+255)/256,256,0,stream>>>(W1, W1T, 1024, 1);
  k_wcvt<<<(128*128+255)/256,256,0,stream>>>(W2, W2T, 128, 1);
  k_wcvt<<<(128*128+255)/256,256,0,stream>>>(Wdo, WdoB, 128, 0);
  // CSR build
  k_deg <<<EE/256, 256, 0, stream>>>(esrc, edst, dout_, din_);
  k_norminv<<<(NN+255)/256, 256, 0, stream>>>(dout_, din_, perm, ns, nd, inv);
  k_scan1<<<SCB, 1024, 0, stream>>>(din_, chunk, bsum);
  k_scan2<<<1, 128, 0, stream>>>(bsum, bpre, row_ptr);
  k_scan3<<<(NN+255)/256, 256, 0, stream>>>(din_, chunk, bpre, row_ptr, cursor);
  k_fill<<<EE/256, 256, 0, stream>>>(esrc, edst, cursor, colx);

  int gb1 = (NN + 63)/64;
  int gb2 = (2*NN + 63)/64;
  // GC1: z = x@W1 once; epilogue writes zs and zp (scatter by inv-perm)
  k_gemmA<1024,0,0><<<gb1,256,0,stream>>>(x, W1T, zs, zp, ns, inv, nullptr, NN);
  k_agg128<false><<<(NN+3)/4,256,0,stream>>>(zs, zp, row_ptr, colx, nd, b1, o1, o2, nullptr);
  // GC2 fused over both encodes (o1||o2 contiguous), +residual agg (fuses rn)
  k_gemmA<128,0,1><<<gb2,256,0,stream>>>(o1, W2T, zs, nullptr, ns, nullptr, nullptr, 2*NN);
  k_agg128<true><<<(NN+3)/4,256,0,stream>>>(zs, zp, row_ptr, colx, nd, b2, o1, o2, rn);
  // GC3 fused
  k_gemm3<<<(2*NN+15)/16,256,0,stream>>>(o1, W3, ns, th, 2*NN);
  k_agg16<<<(NN+15)/16,256,0,stream>>>(th, th + (size_t)NN*16, row_ptr, colx, nd, b3, out_h, h2);
  // discriminator (o-path): v = sigm(relu(o)*rn) @ Wdo^T, fused over both encodes
  k_gemmA<128,1,2><<<gb2,256,0,stream>>>(o1, WdoB, zs, nullptr, nullptr, nullptr, rn, 2*NN);
  k_ret_o<<<(NN+3)/4,256,0,stream>>>(o1, o2, zs, zp, bdo, out_ro, out_roa);
  // discriminator (h-path)
  k_ret_h<<<(NN+255)/256,256,0,stream>>>(out_h, h2, Wdh, bdh, out_rh, out_rha);
}

// Round 3
// 900.468 us; speedup vs baseline: 1.3350x; 1.0373x over previous
//
#include <hip/hip_runtime.h>
#include <math.h>

#define NN 100000
#define EE 1600000
#define SCB 98  // ceil(NN/1024)

typedef __attribute__((ext_vector_type(8))) short bf16x8;
typedef __attribute__((ext_vector_type(4))) float f32x4;

__device__ __forceinline__ unsigned short f2bf(float x){
  union { float f; unsigned u; } v; v.f = x;
  unsigned r = v.u + 0x7FFFu + ((v.u >> 16) & 1u);
  return (unsigned short)(r >> 16);
}
__device__ __forceinline__ float bf2f(unsigned short h){
  union { unsigned u; float f; } v; v.u = ((unsigned)h) << 16; return v.f;
}
__device__ __forceinline__ float sigm(float x){ return 1.0f/(1.0f+expf(-x)); }

// ---------------- degree ----------------
__global__ __launch_bounds__(256) void k_deg(const int* __restrict__ src, const int* __restrict__ dst,
                      int* __restrict__ dout, int* __restrict__ din){
  int e = blockIdx.x*256 + threadIdx.x;
  if (e < EE){ atomicAdd(&dout[src[e]],1); atomicAdd(&din[dst[e]],1); }
}

__global__ __launch_bounds__(256) void k_norminv(const int* __restrict__ dout, const int* __restrict__ din,
                       const int* __restrict__ perm,
                       float* __restrict__ ns, float* __restrict__ nd, int* __restrict__ inv){
  int n = blockIdx.x*256+threadIdx.x;
  if (n < NN){
    ns[n] = rsqrtf((float)max(dout[n],1));
    nd[n] = rsqrtf((float)max(din[n],1));
    inv[perm[n]] = n;
  }
}

// ---------------- parallel scan (3 phases) ----------------
__global__ __launch_bounds__(1024) void k_scan1(const int* __restrict__ din, int* __restrict__ chunk,
                        int* __restrict__ bsum){
  __shared__ int wsum[16];
  int t = threadIdx.x, lane = t & 63, w = t >> 6;
  int i = blockIdx.x*1024 + t;
  int v = (i < NN) ? din[i] : 0;
  int x = v;
  #pragma unroll
  for (int off=1; off<64; off<<=1){
    int y = __shfl_up(x, off);
    if (lane>=off) x += y;
  }
  if (lane==63) wsum[w] = x;
  __syncthreads();
  int pre = 0;
  #pragma unroll
  for (int j=0;j<16;j++) if (j<w) pre += wsum[j];
  int incl = x + pre;
  if (i < NN) chunk[i] = incl;
  if (t == 1023) bsum[blockIdx.x] = incl;
}

__global__ __launch_bounds__(128) void k_scan2(const int* __restrict__ bsum, int* __restrict__ bpre,
                       int* __restrict__ row_ptr){
  __shared__ int w0tot;
  int t = threadIdx.x, lane = t & 63, w = t >> 6;
  int v = (t < SCB) ? bsum[t] : 0;
  int x = v;
  #pragma unroll
  for (int off=1; off<64; off<<=1){
    int y = __shfl_up(x, off);
    if (lane>=off) x += y;
  }
  if (w==0 && lane==63) w0tot = x;
  __syncthreads();
  int incl = x + (w ? w0tot : 0);
  if (t < SCB) bpre[t] = incl - v;
  if (t == 0) row_ptr[0] = 0;
}

__global__ __launch_bounds__(256) void k_scan3(const int* __restrict__ din, const int* __restrict__ chunk,
                       const int* __restrict__ bpre,
                       int* __restrict__ row_ptr, int* __restrict__ cursor){
  int i = blockIdx.x*256 + threadIdx.x;
  if (i < NN){
    int val = chunk[i] + bpre[i>>10];
    row_ptr[i+1] = val;
    cursor[i] = val - din[i];
  }
}

__global__ __launch_bounds__(256) void k_fill(const int* __restrict__ src, const int* __restrict__ dst,
                       int* __restrict__ cursor, int* __restrict__ col){
  int e = blockIdx.x*256+threadIdx.x;
  if (e<EE){ int pos = atomicAdd(&cursor[dst[e]],1); col[pos] = src[e]; }
}

// ---------------- weight convert to chunked-col-major bf16 ----------------
// out[(k>>6)*8192 + col*64 + (k&63)] = bf16( trans ? W[k*128+col] : W[col*K+k] )
__global__ __launch_bounds__(256) void k_wcvt(const float* __restrict__ W, unsigned short* __restrict__ out,
                       int K, int trans){
  int i = blockIdx.x*256 + threadIdx.x;
  if (i >= K*128) return;
  int c = i >> 13;
  int r = i & 8191;
  int col = r >> 6;
  int kk = r & 63;
  int k = c*64 + kk;
  float v = trans ? W[(size_t)k*128 + col] : W[(size_t)col*K + k];
  out[i] = f2bf(v);
}

// ---------------- MFMA GEMM, A direct-to-reg (1-step prefetch), B chunk-dbuf LDS ----------------
// IN_MODE: 0 plain ; 1 sigmoid(relu(a)*rn[row])
// OUT_MODE: 0 zs/zp scatter ; 1 out0[row]=v*scale[row%NN] ; 2 out0[row]=v
// Wc layout: [chunk][col][k-in-chunk] (k_wcvt output), chunk = 64 k
template<int KDIM, int IN_MODE, int OUT_MODE>
__global__ __launch_bounds__(256) void k_gemmA(
    const float* __restrict__ A, const unsigned short* __restrict__ Wc,
    unsigned short* __restrict__ out0, unsigned short* __restrict__ out1,
    const float* __restrict__ scale, const int* __restrict__ inv,
    const float* __restrict__ rn, int nrows)
{
  constexpr int NSTEP = KDIM/32, NC = KDIM/64, SBS = 72;  // stride shorts per col (64+8 pad)
  __shared__ __align__(16) unsigned short Bs[2*128*SBS];
  int t = threadIdx.x, wave = t>>6, lane = t&63;
  int row0 = blockIdx.x*64;
  int arow = row0 + wave*16 + (lane&15);
  int kof = (lane>>4)*8;
  int arow_c = min(arow, nrows-1);
  const float* ap = A + (size_t)arow_c*KDIM + kof;
  float rscale = 1.0f;
  if constexpr (IN_MODE==1) rscale = rn[arow_c];

  // B stage mapping: piece j (0..3): global short-off = c*8192 + j*2048 + t*8
  //                  LDS: col = j*32 + (t>>3), kk = (t&7)*8
  int scol = t>>3, skk = (t&7)*8;

  unsigned short* b0 = &Bs[0];
  unsigned short* b1 = &Bs[128*SBS];
  const unsigned short* bcur = b0;
  unsigned short* bnxt = b1;

  f32x4 acc[8] = {};
  float4 na0, na1;
  bf16x8 w0, w1, w2, w3;

  // prologue: stage chunk 0, load A step 0
  {
    const unsigned short* gp = Wc + (size_t)t*8;
    bf16x8 t0 = *(const bf16x8*)(gp);
    bf16x8 t1 = *(const bf16x8*)(gp + 2048);
    bf16x8 t2 = *(const bf16x8*)(gp + 4096);
    bf16x8 t3 = *(const bf16x8*)(gp + 6144);
    *(bf16x8*)&b0[(0*32 + scol)*SBS + skk] = t0;
    *(bf16x8*)&b0[(1*32 + scol)*SBS + skk] = t1;
    *(bf16x8*)&b0[(2*32 + scol)*SBS + skk] = t2;
    *(bf16x8*)&b0[(3*32 + scol)*SBS + skk] = t3;
    na0 = *(const float4*)(ap);
    na1 = *(const float4*)(ap + 4);
  }
  __syncthreads();

  #pragma unroll
  for (int s = 0; s < NSTEP; ++s){
    const int c = s >> 1;
    // issue next-chunk B loads at chunk start
    if ((s & 1) == 0 && (c+1) < NC){
      const unsigned short* gp = Wc + (size_t)(c+1)*8192 + (size_t)t*8;
      w0 = *(const bf16x8*)(gp);
      w1 = *(const bf16x8*)(gp + 2048);
      w2 = *(const bf16x8*)(gp + 4096);
      w3 = *(const bf16x8*)(gp + 6144);
    }
    float4 c0 = na0, c1 = na1;
    // issue next-step A loads
    if (s+1 < NSTEP){
      na0 = *(const float4*)(ap + (s+1)*32);
      na1 = *(const float4*)(ap + (s+1)*32 + 4);
    }
    float av[8] = {c0.x,c0.y,c0.z,c0.w,c1.x,c1.y,c1.z,c1.w};
    if constexpr (IN_MODE==1){
      #pragma unroll
      for (int i=0;i<8;i++) av[i] = sigm(fmaxf(av[i],0.0f)*rscale);
    }
    bf16x8 afrag;
    #pragma unroll
    for (int i=0;i<8;i++) afrag[i] = (short)f2bf(av[i]);
    int kbase = (s & 1)*32 + kof;
    #pragma unroll
    for (int j=0;j<8;j++){
      bf16x8 b = *(const bf16x8*)&bcur[(j*16 + (lane&15))*SBS + kbase];
      acc[j] = __builtin_amdgcn_mfma_f32_16x16x32_bf16(afrag, b, acc[j], 0, 0, 0);
    }
    if ((s & 1) == 1 && (c+1) < NC){
      *(bf16x8*)&bnxt[(0*32 + scol)*SBS + skk] = w0;
      *(bf16x8*)&bnxt[(1*32 + scol)*SBS + skk] = w1;
      *(bf16x8*)&bnxt[(2*32 + scol)*SBS + skk] = w2;
      *(bf16x8*)&bnxt[(3*32 + scol)*SBS + skk] = w3;
      __syncthreads();
      const unsigned short* tmp = bcur; bcur = bnxt; bnxt = (unsigned short*)tmp;
    }
  }

  // epilogue: C/D layout col=lane&15, row=(lane>>4)*4+reg
  int rbase = row0 + wave*16 + (lane>>4)*4;
  int c = lane & 15;
  #pragma unroll
  for (int j=0;j<8;j++){
    int colx = j*16 + c;
    #pragma unroll
    for (int r=0;r<4;r++){
      int row = rbase + r;
      if (row < nrows){
        float v = acc[j][r];
        if constexpr (OUT_MODE==0){
          out0[(size_t)row*128 + colx] = f2bf(v * scale[row]);
          int ir = inv[row];
          out1[(size_t)ir*128 + colx] = f2bf(v * scale[ir]);
        } else if constexpr (OUT_MODE==1){
          int sidx = row >= NN ? row - NN : row;
          out0[(size_t)row*128 + colx] = f2bf(v * scale[sidx]);
        } else {
          out0[(size_t)row*128 + colx] = f2bf(v);
        }
      }
    }
  }
}

// ---------------- CSR aggregation, width 128, 16B/lane, 4 edges in flight ----------------
template<bool RESID>
__global__ __launch_bounds__(256) void k_agg128(
  const unsigned short* __restrict__ va, const unsigned short* __restrict__ vb,
  const int* __restrict__ row_ptr, const int* __restrict__ col,
  const float* __restrict__ nd, const float* __restrict__ bias,
  float* __restrict__ oa, float* __restrict__ ob, float* __restrict__ rn)
{
  int wave = threadIdx.x >> 6, lane = threadIdx.x & 63;
  int row = blockIdx.x * 4 + wave;
  if (row >= NN) return;
  int s = row_ptr[row], e = row_ptr[row+1];
  int eg = lane >> 4;
  int c8 = (lane & 15) * 8;
  float accA[8] = {}, accB[8] = {};
  for (int i = s + eg; i < e; i += 4){
    int scn = col[i];
    bf16x8 ua = *(const bf16x8*)(va + (size_t)scn*128 + c8);
    bf16x8 ub = *(const bf16x8*)(vb + (size_t)scn*128 + c8);
    #pragma unroll
    for (int j=0;j<8;j++){
      accA[j] += bf2f((unsigned short)ua[j]);
      accB[j] += bf2f((unsigned short)ub[j]);
    }
  }
  #pragma unroll
  for (int j=0;j<8;j++){
    accA[j] += __shfl_down(accA[j], 32); accA[j] += __shfl_down(accA[j], 16);
    accB[j] += __shfl_down(accB[j], 32); accB[j] += __shfl_down(accB[j], 16);
  }
  if (lane < 16){
    float ndr = nd[row];
    size_t o = (size_t)row*128 + c8;
    float ra[8], rb[8];
    #pragma unroll
    for (int j=0;j<8;j++){
      ra[j] = accA[j]*ndr + bias[c8+j];
      rb[j] = accB[j]*ndr + bias[c8+j];
    }
    if constexpr (RESID){
      float4 p0 = *(const float4*)(oa+o);
      float4 p1 = *(const float4*)(oa+o+4);
      float4 q0 = *(const float4*)(ob+o);
      float4 q1 = *(const float4*)(ob+o+4);
      ra[0]+=p0.x; ra[1]+=p0.y; ra[2]+=p0.z; ra[3]+=p0.w;
      ra[4]+=p1.x; ra[5]+=p1.y; ra[6]+=p1.z; ra[7]+=p1.w;
      rb[0]+=q0.x; rb[1]+=q0.y; rb[2]+=q0.z; rb[3]+=q0.w;
      rb[4]+=q1.x; rb[5]+=q1.y; rb[6]+=q1.z; rb[7]+=q1.w;
    }
    *(float4*)(oa+o)   = make_float4(ra[0],ra[1],ra[2],ra[3]);
    *(float4*)(oa+o+4) = make_float4(ra[4],ra[5],ra[6],ra[7]);
    *(float4*)(ob+o)   = make_float4(rb[0],rb[1],rb[2],rb[3]);
    *(float4*)(ob+o+4) = make_float4(rb[4],rb[5],rb[6],rb[7]);
    if constexpr (RESID){
      float sa = 0.f, sb = 0.f;
      #pragma unroll
      for (int j=0;j<8;j++){
        float x1 = fmaxf(ra[j],0.f), x2 = fmaxf(rb[j],0.f);
        sa += x1*x1; sb += x2*x2;
      }
      #pragma unroll
      for (int off=8; off>0; off>>=1){
        sa += __shfl_down(sa, off);
        sb += __shfl_down(sb, off);
      }
      if (lane==0){
        rn[row]      = 1.0f / fmaxf(sqrtf(sa), 1e-12f);
        rn[NN + row] = 1.0f / fmaxf(sqrtf(sb), 1e-12f);
      }
    }
  }
}

// ---------------- width-16 aggregation (GC3) ----------------
__global__ __launch_bounds__(256) void k_agg16(
  const unsigned short* __restrict__ va, const unsigned short* __restrict__ vb,
  const int* __restrict__ row_ptr, const int* __restrict__ col,
  const float* __restrict__ nd, const float* __restrict__ b3,
  float* __restrict__ hout, float* __restrict__ h2)
{
  int t = threadIdx.x;
  int row = blockIdx.x*16 + (t>>4);
  int c = t & 15;
  if (row >= NN) return;
  int s = row_ptr[row], e = row_ptr[row+1];
  float aa=0.f, ab=0.f;
  for (int i=s;i<e;i++){
    int sc = col[i];
    aa += bf2f(va[(size_t)sc*16 + c]);
    ab += bf2f(vb[(size_t)sc*16 + c]);
  }
  float ndr = nd[row]; float bb = b3[c];
  hout[(size_t)row*16+c] = aa*ndr + bb;
  h2  [(size_t)row*16+c] = ab*ndr + bb;
}

// ---------------- GC3 mult (fused over 2*NN rows): th = (o @ W3) * ns[row%NN] ----------------
__global__ __launch_bounds__(256) void k_gemm3(const float* __restrict__ o, const float* __restrict__ W3,
     const float* __restrict__ ns, unsigned short* __restrict__ th, int nrows)
{
  __shared__ float Ws[128*16];
  int t = threadIdx.x;
  for (int i=t;i<2048;i+=256) Ws[i]=W3[i];
  __syncthreads();
  int row = blockIdx.x*16 + (t>>4);
  int c = t & 15;
  if (row >= nrows) return;
  const float* p = o + (size_t)row*128;
  float acc=0.f;
  #pragma unroll 4
  for (int k4=0;k4<32;k4++){
    float4 v = *(const float4*)(p + k4*4);
    acc += v.x*Ws[(k4*4+0)*16+c] + v.y*Ws[(k4*4+1)*16+c]
         + v.z*Ws[(k4*4+2)*16+c] + v.w*Ws[(k4*4+3)*16+c];
  }
  int sidx = row >= NN ? row - NN : row;
  th[(size_t)row*16+c] = f2bf(acc*ns[sidx]);
}

// ---------------- ret_o / ret_oa ----------------
__global__ __launch_bounds__(256) void k_ret_o(const float* __restrict__ o1, const float* __restrict__ o2,
  const unsigned short* __restrict__ v1, const unsigned short* __restrict__ v2,
  const float* __restrict__ bdo, float* __restrict__ ro, float* __restrict__ roa)
{
  int wave = threadIdx.x>>6, lane = threadIdx.x&63;
  int row = blockIdx.x*4+wave;
  if (row>=NN) return;
  size_t base = (size_t)row*128 + lane*2;
  float e0a = fmaxf(o1[base],0.f),  e0b = fmaxf(o1[base+1],0.f);
  float e1a = fmaxf(o2[base],0.f),  e1b = fmaxf(o2[base+1],0.f);
  unsigned u1 = *(const unsigned*)(v1+base);
  unsigned u2 = *(const unsigned*)(v2+base);
  float v1a = bf2f((unsigned short)u1), v1b = bf2f((unsigned short)(u1>>16));
  float v2a = bf2f((unsigned short)u2), v2b = bf2f((unsigned short)(u2>>16));
  float d00 = e0a*v1a + e0b*v1b;
  float d01 = e1a*v1a + e1b*v1b;
  float d10 = e1a*v2a + e1b*v2b;
  float d11 = e0a*v2a + e0b*v2b;
  #pragma unroll
  for (int off=32; off>0; off>>=1){
    d00 += __shfl_down(d00, off);
    d01 += __shfl_down(d01, off);
    d10 += __shfl_down(d10, off);
    d11 += __shfl_down(d11, off);
  }
  if (lane==0){
    float bb = bdo[0];
    ro [(size_t)row*2+0] = d00+bb;
    ro [(size_t)row*2+1] = d01+bb;
    roa[(size_t)row*2+0] = d10+bb;
    roa[(size_t)row*2+1] = d11+bb;
  }
}

// ---------------- ret_h / ret_ha ----------------
__global__ __launch_bounds__(256) void k_ret_h(const float* __restrict__ h1, const float* __restrict__ h2,
  const float* __restrict__ Wdh, const float* __restrict__ bdh,
  float* __restrict__ rh, float* __restrict__ rha)
{
  __shared__ float Ws[256];
  int t = threadIdx.x;
  if (t<256) Ws[t]=Wdh[t];
  __syncthreads();
  int n = blockIdx.x*256 + t;
  if (n>=NN) return;
  float e1[16], e2[16];
  float s1=0.f, s2=0.f;
  const float* p1 = h1 + (size_t)n*16;
  const float* p2 = h2 + (size_t)n*16;
  #pragma unroll
  for (int i=0;i<16;i++){
    e1[i]=fmaxf(p1[i],0.f); s1+=e1[i]*e1[i];
    e2[i]=fmaxf(p2[i],0.f); s2+=e2[i]*e2[i];
  }
  float r1 = 1.0f/fmaxf(sqrtf(s1),1e-12f);
  float r2 = 1.0f/fmaxf(sqrtf(s2),1e-12f);
  float g1[16], g2[16];
  #pragma unroll
  for (int i=0;i<16;i++){ g1[i]=sigm(e1[i]*r1); g2[i]=sigm(e2[i]*r2); }
  float q00=0.f,q01=0.f,q10=0.f,q11=0.f;
  #pragma unroll
  for (int d=0; d<16; d++){
    float vh1=0.f, vh2=0.f;
    #pragma unroll
    for (int e=0;e<16;e++){ vh1 += Ws[d*16+e]*g1[e]; vh2 += Ws[d*16+e]*g2[e]; }
    q00 += e1[d]*vh1; q01 += e2[d]*vh1;
    q10 += e2[d]*vh2; q11 += e1[d]*vh2;
  }
  float bb = bdh[0];
  rh [(size_t)n*2+0]=q00+bb; rh [(size_t)n*2+1]=q01+bb;
  rha[(size_t)n*2+0]=q10+bb; rha[(size_t)n*2+1]=q11+bb;
}

// ---------------- launch ----------------
extern "C" void kernel_launch(void* const* d_in, const int* in_sizes, int n_in,
                              void* d_out, int out_size, void* d_ws, size_t ws_size,
                              hipStream_t stream){
  const float* x   = (const float*)d_in[0];
  const float* W1  = (const float*)d_in[1];
  const float* b1  = (const float*)d_in[2];
  const float* W2  = (const float*)d_in[3];
  const float* b2  = (const float*)d_in[4];
  const float* W3  = (const float*)d_in[5];
  const float* b3  = (const float*)d_in[6];
  const float* Wdo = (const float*)d_in[7];
  const float* bdo = (const float*)d_in[8];
  const float* Wdh = (const float*)d_in[9];
  const float* bdh = (const float*)d_in[10];
  const int* ei    = (const int*)d_in[11];
  const int* perm  = (const int*)d_in[12];
  const int* esrc = ei;
  const int* edst = ei + EE;

  char* ws = (char*)d_ws;
  size_t off = 0;
  auto alloc = [&](size_t bytes)->void*{ void* p = ws + off; off += (bytes + 255) & ~(size_t)255; return p; };
  unsigned short* zs = (unsigned short*)alloc((size_t)NN*128*2);   // also t1 / v1
  unsigned short* zp = (unsigned short*)alloc((size_t)NN*128*2);   // also t2 / v2 (contiguous with zs)
  float* o1 = (float*)alloc((size_t)NN*128*4);
  float* o2 = (float*)alloc((size_t)NN*128*4);                    // contiguous with o1
  unsigned short* th = (unsigned short*)alloc((size_t)2*NN*16*2);
  float* h2 = (float*)alloc((size_t)NN*16*4);
  int* deg = (int*)alloc((size_t)2*NN*4);
  int* dout_ = deg; int* din_ = deg + NN;
  float* ns = (float*)alloc((size_t)NN*4);
  float* nd = (float*)alloc((size_t)NN*4);
  int* inv  = (int*)alloc((size_t)NN*4);
  float* rn = (float*)alloc((size_t)2*NN*4);
  int* cursor = (int*)alloc((size_t)NN*4);
  int* row_ptr = (int*)alloc((size_t)(NN+1)*4);
  int* colx = (int*)alloc((size_t)EE*4);
  int* chunk = (int*)alloc((size_t)NN*4);
  int* bsum = (int*)alloc((size_t)SCB*4);
  int* bpre = (int*)alloc((size_t)SCB*4);
  unsigned short* W1T = (unsigned short*)alloc((size_t)1024*128*2);
  unsigned short* W2T = (unsigned short*)alloc((size_t)128*128*2);
  unsigned short* WdoB = (unsigned short*)alloc((size_t)128*128*2);

  float* out_h   = (float*)d_out;
  float* out_ro  = out_h  + (size_t)NN*16;
  float* out_rh  = out_ro + (size_t)NN*2;
  float* out_roa = out_rh + (size_t)NN*2;
  float* out_rha = out_roa+ (size_t)NN*2;

  hipMemsetAsync(deg, 0, (size_t)2*NN*4, stream);
  // weight preconversion (independent) -> chunked layout
  k_wcvt<<<(1024*128+255)/256,256,0,stream>>>(W1, W1T, 1024, 1);
  k_wcvt<<<(128*128+255)/256,256,0,stream>>>(W2, W2T, 128, 1);
  k_wcvt<<<(128*128+255)/256,256,0,stream>>>(Wdo, WdoB, 128, 0);
  // CSR build
  k_deg <<<EE/256, 256, 0, stream>>>(esrc, edst, dout_, din_);
  k_norminv<<<(NN+255)/256, 256, 0, stream>>>(dout_, din_, perm, ns, nd, inv);
  k_scan1<<<SCB, 1024, 0, stream>>>(din_, chunk, bsum);
  k_scan2<<<1, 128, 0, stream>>>(bsum, bpre, row_ptr);
  k_scan3<<<(NN+255)/256, 256, 0, stream>>>(din_, chunk, bpre, row_ptr, cursor);
  k_fill<<<EE/256, 256, 0, stream>>>(esrc, edst, cursor, colx);

  int gb1 = (NN + 63)/64;
  int gb2 = (2*NN + 63)/64;
  // GC1: z = x@W1 once; epilogue writes zs and zp (scatter by inv-perm)
  k_gemmA<1024,0,0><<<gb1,256,0,stream>>>(x, W1T, zs, zp, ns, inv, nullptr, NN);
  k_agg128<false><<<(NN+3)/4,256,0,stream>>>(zs, zp, row_ptr, colx, nd, b1, o1, o2, nullptr);
  // GC2 fused over both encodes (o1||o2 contiguous), +residual agg (fuses rn)
  k_gemmA<128,0,1><<<gb2,256,0,stream>>>(o1, W2T, zs, nullptr, ns, nullptr, nullptr, 2*NN);
  k_agg128<true><<<(NN+3)/4,256,0,stream>>>(zs, zp, row_ptr, colx, nd, b2, o1, o2, rn);
  // GC3 fused
  k_gemm3<<<(2*NN+15)/16,256,0,stream>>>(o1, W3, ns, th, 2*NN);
  k_agg16<<<(NN+15)/16,256,0,stream>>>(th, th + (size_t)NN*16, row_ptr, colx, nd, b3, out_h, h2);
  // discriminator (o-path): v = sigm(relu(o)*rn) @ Wdo^T, fused over both encodes
  k_gemmA<128,1,2><<<gb2,256,0,stream>>>(o1, WdoB, zs, nullptr, nullptr, nullptr, rn, 2*NN);
  k_ret_o<<<(NN+3)/4,256,0,stream>>>(o1, o2, zs, zp, bdo, out_ro, out_roa);
  // discriminator (h-path)
  k_ret_h<<<(NN+255)/256,256,0,stream>>>(out_h, h2, Wdh, bdh, out_rh, out_rha);
}

// Round 4
// 821.191 us; speedup vs baseline: 1.4638x; 1.0965x over previous
//
#include <hip/hip_runtime.h>
#include <math.h>

#define NN 100000
#define EE 1600000
#define SCB 98  // ceil(NN/1024)

typedef __attribute__((ext_vector_type(8))) short bf16x8;
typedef __attribute__((ext_vector_type(4))) float f32x4;

__device__ __forceinline__ unsigned short f2bf(float x){
  union { float f; unsigned u; } v; v.f = x;
  unsigned r = v.u + 0x7FFFu + ((v.u >> 16) & 1u);
  return (unsigned short)(r >> 16);
}
__device__ __forceinline__ float bf2f(unsigned short h){
  union { unsigned u; float f; } v; v.u = ((unsigned)h) << 16; return v.f;
}
__device__ __forceinline__ float sigm(float x){ return 1.0f/(1.0f+expf(-x)); }

// ---------------- degree ----------------
__global__ __launch_bounds__(256) void k_deg(const int* __restrict__ src, const int* __restrict__ dst,
                      int* __restrict__ dout, int* __restrict__ din){
  int e = blockIdx.x*256 + threadIdx.x;
  if (e < EE){ atomicAdd(&dout[src[e]],1); atomicAdd(&din[dst[e]],1); }
}

__global__ __launch_bounds__(256) void k_norminv(const int* __restrict__ dout, const int* __restrict__ din,
                       const int* __restrict__ perm,
                       float* __restrict__ ns, float* __restrict__ nd, int* __restrict__ inv){
  int n = blockIdx.x*256+threadIdx.x;
  if (n < NN){
    ns[n] = rsqrtf((float)max(dout[n],1));
    nd[n] = rsqrtf((float)max(din[n],1));
    inv[perm[n]] = n;
  }
}

// ---------------- parallel scan (3 phases) ----------------
__global__ __launch_bounds__(1024) void k_scan1(const int* __restrict__ din, int* __restrict__ chunk,
                        int* __restrict__ bsum){
  __shared__ int wsum[16];
  int t = threadIdx.x, lane = t & 63, w = t >> 6;
  int i = blockIdx.x*1024 + t;
  int v = (i < NN) ? din[i] : 0;
  int x = v;
  #pragma unroll
  for (int off=1; off<64; off<<=1){
    int y = __shfl_up(x, off);
    if (lane>=off) x += y;
  }
  if (lane==63) wsum[w] = x;
  __syncthreads();
  int pre = 0;
  #pragma unroll
  for (int j=0;j<16;j++) if (j<w) pre += wsum[j];
  int incl = x + pre;
  if (i < NN) chunk[i] = incl;
  if (t == 1023) bsum[blockIdx.x] = incl;
}

__global__ __launch_bounds__(128) void k_scan2(const int* __restrict__ bsum, int* __restrict__ bpre,
                       int* __restrict__ row_ptr){
  __shared__ int w0tot;
  int t = threadIdx.x, lane = t & 63, w = t >> 6;
  int v = (t < SCB) ? bsum[t] : 0;
  int x = v;
  #pragma unroll
  for (int off=1; off<64; off<<=1){
    int y = __shfl_up(x, off);
    if (lane>=off) x += y;
  }
  if (w==0 && lane==63) w0tot = x;
  __syncthreads();
  int incl = x + (w ? w0tot : 0);
  if (t < SCB) bpre[t] = incl - v;
  if (t == 0) row_ptr[0] = 0;
}

__global__ __launch_bounds__(256) void k_scan3(const int* __restrict__ din, const int* __restrict__ chunk,
                       const int* __restrict__ bpre,
                       int* __restrict__ row_ptr, int* __restrict__ cursor){
  int i = blockIdx.x*256 + threadIdx.x;
  if (i < NN){
    int val = chunk[i] + bpre[i>>10];
    row_ptr[i+1] = val;
    cursor[i] = val - din[i];
  }
}

__global__ __launch_bounds__(256) void k_fill(const int* __restrict__ src, const int* __restrict__ dst,
                       int* __restrict__ cursor, int* __restrict__ col){
  int e = blockIdx.x*256+threadIdx.x;
  if (e<EE){ int pos = atomicAdd(&cursor[dst[e]],1); col[pos] = src[e]; }
}

// ---------------- weight convert to chunked-col-major bf16 ----------------
// out[(k>>6)*8192 + col*64 + (k&63)] = bf16( trans ? W[k*128+col] : W[col*K+k] )
__global__ __launch_bounds__(256) void k_wcvt(const float* __restrict__ W, unsigned short* __restrict__ out,
                       int K, int trans){
  int i = blockIdx.x*256 + threadIdx.x;
  if (i >= K*128) return;
  int c = i >> 13;
  int r = i & 8191;
  int col = r >> 6;
  int kk = r & 63;
  int k = c*64 + kk;
  float v = trans ? W[(size_t)k*128 + col] : W[(size_t)col*K + k];
  out[i] = f2bf(v);
}

// ---------------- A-fragment holders ----------------
struct ARF { float4 a, b; };
struct ARU { bf16x8 a; };
__device__ __forceinline__ void aload(ARF& r, const float* p){
  r.a = *(const float4*)p; r.b = *(const float4*)(p+4);
}
__device__ __forceinline__ void aload(ARU& r, const unsigned short* p){
  r.a = *(const bf16x8*)p;
}
template<int IM>
__device__ __forceinline__ bf16x8 aconv(const ARF& r, float rs){
  float av[8] = {r.a.x,r.a.y,r.a.z,r.a.w,r.b.x,r.b.y,r.b.z,r.b.w};
  if constexpr (IM==1){
    #pragma unroll
    for (int i=0;i<8;i++) av[i] = sigm(fmaxf(av[i],0.0f)*rs);
  }
  bf16x8 o;
  #pragma unroll
  for (int i=0;i<8;i++) o[i] = (short)f2bf(av[i]);
  return o;
}
template<int IM>
__device__ __forceinline__ bf16x8 aconv(const ARU& r, float rs){
  if constexpr (IM==0) return r.a;
  else {
    bf16x8 o;
    #pragma unroll
    for (int i=0;i<8;i++){
      float v = sigm(fmaxf(bf2f((unsigned short)r.a[i]),0.0f)*rs);
      o[i] = (short)f2bf(v);
    }
    return o;
  }
}
template<typename T> struct ARofT;
template<> struct ARofT<float>{ using type = ARF; };
template<> struct ARofT<unsigned short>{ using type = ARU; };

// ---------------- MFMA GEMM, A direct-to-reg (2-chunk prefetch), B chunk-dbuf LDS ----------------
// IN_MODE: 0 plain ; 1 sigmoid(relu(a)*rn[row])
// OUT_MODE: 0 zs/zp scatter (bf16) ; 1 out0[row]=v*scale[row%NN] (bf16) ;
//           3 fused discriminator: dots vs relu(o_same/o_other), writes ro/roa (scale=bdo)
// Wc layout: [chunk][col][k-in-chunk], chunk = 64 k
template<int KDIM, int IN_MODE, int OUT_MODE, typename AT>
__global__ __launch_bounds__(256) void k_gemmA(
    const AT* __restrict__ A, const unsigned short* __restrict__ Wc,
    unsigned short* __restrict__ out0, unsigned short* __restrict__ out1,
    const float* __restrict__ scale, const int* __restrict__ inv,
    const float* __restrict__ rn, int nrows,
    float* __restrict__ ro, float* __restrict__ roa)
{
  constexpr int NC = KDIM/64, SBS = 72, OSS = 132;
  __shared__ __align__(16) unsigned short Bs[2*128*SBS];
  int t = threadIdx.x, wave = t>>6, lane = t&63;
  int row0 = blockIdx.x*64;
  int arow = row0 + wave*16 + (lane&15);
  int kof = (lane>>4)*8;
  int arow_c = min(arow, nrows-1);
  const AT* ap = A + (size_t)arow_c*KDIM + kof;
  float rscale = 1.0f;
  if constexpr (IN_MODE==1) rscale = rn[arow_c];

  int scol = t>>3, skk = (t&7)*8;
  unsigned short* b0 = &Bs[0];
  unsigned short* b1 = &Bs[128*SBS];
  const unsigned short* bcur = b0;
  unsigned short* bnxt = b1;

  f32x4 acc[8] = {};
  typename ARofT<AT>::type A0a{}, A0b{}, A1a{}, A1b{}, A2a{}, A2b{};
  bf16x8 w0{}, w1{}, w2{}, w3{};

  // prologue: stage chunk0 B to LDS, load A chunks 0,1, issue B chunk1
  {
    const unsigned short* gp = Wc + (size_t)t*8;
    bf16x8 t0 = *(const bf16x8*)(gp);
    bf16x8 t1 = *(const bf16x8*)(gp + 2048);
    bf16x8 t2 = *(const bf16x8*)(gp + 4096);
    bf16x8 t3 = *(const bf16x8*)(gp + 6144);
    *(bf16x8*)&b0[(0*32 + scol)*SBS + skk] = t0;
    *(bf16x8*)&b0[(1*32 + scol)*SBS + skk] = t1;
    *(bf16x8*)&b0[(2*32 + scol)*SBS + skk] = t2;
    *(bf16x8*)&b0[(3*32 + scol)*SBS + skk] = t3;
  }
  aload(A0a, ap);
  aload(A0b, ap + 32);
  if (NC > 1){
    aload(A1a, ap + 64);
    aload(A1b, ap + 96);
    const unsigned short* gp = Wc + 8192 + (size_t)t*8;
    w0 = *(const bf16x8*)(gp);
    w1 = *(const bf16x8*)(gp + 2048);
    w2 = *(const bf16x8*)(gp + 4096);
    w3 = *(const bf16x8*)(gp + 6144);
  }
  __syncthreads();

  #pragma unroll
  for (int cc=0; cc<NC; ++cc){
    if (cc+2 < NC){
      aload(A2a, ap + (cc+2)*64);
      aload(A2b, ap + (cc+2)*64 + 32);
    }
    // step 0
    {
      bf16x8 af = aconv<IN_MODE>(A0a, rscale);
      #pragma unroll
      for (int j=0;j<8;j++){
        bf16x8 b = *(const bf16x8*)&bcur[(j*16 + (lane&15))*SBS + kof];
        acc[j] = __builtin_amdgcn_mfma_f32_16x16x32_bf16(af, b, acc[j], 0, 0, 0);
      }
    }
    // step 1
    {
      bf16x8 af = aconv<IN_MODE>(A0b, rscale);
      #pragma unroll
      for (int j=0;j<8;j++){
        bf16x8 b = *(const bf16x8*)&bcur[(j*16 + (lane&15))*SBS + 32 + kof];
        acc[j] = __builtin_amdgcn_mfma_f32_16x16x32_bf16(af, b, acc[j], 0, 0, 0);
      }
    }
    if (cc+1 < NC){
      *(bf16x8*)&bnxt[(0*32 + scol)*SBS + skk] = w0;
      *(bf16x8*)&bnxt[(1*32 + scol)*SBS + skk] = w1;
      *(bf16x8*)&bnxt[(2*32 + scol)*SBS + skk] = w2;
      *(bf16x8*)&bnxt[(3*32 + scol)*SBS + skk] = w3;
      __syncthreads();
      const unsigned short* tmp = bcur; bcur = bnxt; bnxt = (unsigned short*)tmp;
      if (cc+2 < NC){
        const unsigned short* gp = Wc + (size_t)(cc+2)*8192 + (size_t)t*8;
        w0 = *(const bf16x8*)(gp);
        w1 = *(const bf16x8*)(gp + 2048);
        w2 = *(const bf16x8*)(gp + 4096);
        w3 = *(const bf16x8*)(gp + 6144);
      }
    }
    A0a = A1a; A0b = A1b; A1a = A2a; A1b = A2b;
  }

  int c = lane & 15;
  if constexpr (OUT_MODE==3){
    // fused discriminator epilogue: dots vs relu(o_same), relu(o_other)
    __syncthreads();
    unsigned short* Os = &Bs[0];
    unsigned short* Oo = &Bs[64*OSS];
    for (int p=t; p<1024; p+=256){
      int r = p>>4, seg = p&15;
      int row = row0 + r;
      int other = row < NN ? row + NN : row - NN;
      *(bf16x8*)&Os[r*OSS + seg*8] = *(const bf16x8*)&A[(size_t)row*128 + seg*8];
      *(bf16x8*)&Oo[r*OSS + seg*8] = *(const bf16x8*)&A[(size_t)other*128 + seg*8];
    }
    __syncthreads();
    float bb = scale[0];
    #pragma unroll
    for (int r=0;r<4;r++){
      int lr = wave*16 + (lane>>4)*4 + r;
      float dsame=0.f, doth=0.f;
      #pragma unroll
      for (int j=0;j<8;j++){
        float v = acc[j][r];
        dsame += fmaxf(bf2f(Os[lr*OSS + j*16 + c]),0.f) * v;
        doth  += fmaxf(bf2f(Oo[lr*OSS + j*16 + c]),0.f) * v;
      }
      #pragma unroll
      for (int off=1; off<16; off<<=1){
        dsame += __shfl_xor(dsame, off);
        doth  += __shfl_xor(doth, off);
      }
      if (c==0){
        int row = row0 + lr;
        if (row < NN){
          ro[(size_t)row*2+0] = dsame + bb;
          ro[(size_t)row*2+1] = doth + bb;
        } else {
          int m = row - NN;
          roa[(size_t)m*2+0] = dsame + bb;
          roa[(size_t)m*2+1] = doth + bb;
        }
      }
    }
  } else {
    // C/D layout col=lane&15, row=(lane>>4)*4+reg
    int rbase = row0 + wave*16 + (lane>>4)*4;
    #pragma unroll
    for (int j=0;j<8;j++){
      int colx = j*16 + c;
      #pragma unroll
      for (int r=0;r<4;r++){
        int row = rbase + r;
        if (row < nrows){
          float v = acc[j][r];
          if constexpr (OUT_MODE==0){
            out0[(size_t)row*128 + colx] = f2bf(v * scale[row]);
            int ir = inv[row];
            out1[(size_t)ir*128 + colx] = f2bf(v * scale[ir]);
          } else {
            int sidx = row >= NN ? row - NN : row;
            out0[(size_t)row*128 + colx] = f2bf(v * scale[sidx]);
          }
        }
      }
    }
  }
}

// ---------------- CSR aggregation, width 128, 16B/lane, 4 edges in flight ----------------
// writes bf16 ob rows [row] (encode1) and [NN+row] (encode2); RESID adds previous + emits rn
template<bool RESID>
__global__ __launch_bounds__(256) void k_agg128(
  const unsigned short* __restrict__ va, const unsigned short* __restrict__ vb,
  const int* __restrict__ row_ptr, const int* __restrict__ col,
  const float* __restrict__ nd, const float* __restrict__ bias,
  unsigned short* __restrict__ ob, float* __restrict__ rn)
{
  int wave = threadIdx.x >> 6, lane = threadIdx.x & 63;
  int row = blockIdx.x * 4 + wave;
  if (row >= NN) return;
  int s = row_ptr[row], e = row_ptr[row+1];
  int eg = lane >> 4;
  int c8 = (lane & 15) * 8;
  float accA[8] = {}, accB[8] = {};
  for (int i = s + eg; i < e; i += 4){
    int scn = col[i];
    bf16x8 ua = *(const bf16x8*)(va + (size_t)scn*128 + c8);
    bf16x8 ub = *(const bf16x8*)(vb + (size_t)scn*128 + c8);
    #pragma unroll
    for (int j=0;j<8;j++){
      accA[j] += bf2f((unsigned short)ua[j]);
      accB[j] += bf2f((unsigned short)ub[j]);
    }
  }
  #pragma unroll
  for (int j=0;j<8;j++){
    accA[j] += __shfl_down(accA[j], 32); accA[j] += __shfl_down(accA[j], 16);
    accB[j] += __shfl_down(accB[j], 32); accB[j] += __shfl_down(accB[j], 16);
  }
  if (lane < 16){
    float ndr = nd[row];
    float4 bv0 = *(const float4*)(bias + c8);
    float4 bv1 = *(const float4*)(bias + c8 + 4);
    float bvv[8] = {bv0.x,bv0.y,bv0.z,bv0.w,bv1.x,bv1.y,bv1.z,bv1.w};
    size_t o1off = (size_t)row*128 + c8;
    size_t o2off = (size_t)(NN+row)*128 + c8;
    float ra[8], rb[8];
    #pragma unroll
    for (int j=0;j<8;j++){
      ra[j] = accA[j]*ndr + bvv[j];
      rb[j] = accB[j]*ndr + bvv[j];
    }
    if constexpr (RESID){
      bf16x8 pa = *(const bf16x8*)(ob + o1off);
      bf16x8 pb = *(const bf16x8*)(ob + o2off);
      #pragma unroll
      for (int j=0;j<8;j++){
        ra[j] += bf2f((unsigned short)pa[j]);
        rb[j] += bf2f((unsigned short)pb[j]);
      }
    }
    bf16x8 wa, wb;
    #pragma unroll
    for (int j=0;j<8;j++){
      wa[j] = (short)f2bf(ra[j]);
      wb[j] = (short)f2bf(rb[j]);
    }
    *(bf16x8*)(ob + o1off) = wa;
    *(bf16x8*)(ob + o2off) = wb;
    if constexpr (RESID){
      float sa = 0.f, sb = 0.f;
      #pragma unroll
      for (int j=0;j<8;j++){
        float x1 = fmaxf(ra[j],0.f), x2 = fmaxf(rb[j],0.f);
        sa += x1*x1; sb += x2*x2;
      }
      #pragma unroll
      for (int off=8; off>0; off>>=1){
        sa += __shfl_down(sa, off);
        sb += __shfl_down(sb, off);
      }
      if (lane==0){
        rn[row]      = 1.0f / fmaxf(sqrtf(sa), 1e-12f);
        rn[NN + row] = 1.0f / fmaxf(sqrtf(sb), 1e-12f);
      }
    }
  }
}

// ---------------- width-16 aggregation (GC3) ----------------
__global__ __launch_bounds__(256) void k_agg16(
  const unsigned short* __restrict__ va, const unsigned short* __restrict__ vb,
  const int* __restrict__ row_ptr, const int* __restrict__ col,
  const float* __restrict__ nd, const float* __restrict__ b3,
  float* __restrict__ hout, float* __restrict__ h2)
{
  int t = threadIdx.x;
  int row = blockIdx.x*16 + (t>>4);
  int c = t & 15;
  if (row >= NN) return;
  int s = row_ptr[row], e = row_ptr[row+1];
  float aa=0.f, ab=0.f;
  for (int i=s;i<e;i++){
    int sc = col[i];
    aa += bf2f(va[(size_t)sc*16 + c]);
    ab += bf2f(vb[(size_t)sc*16 + c]);
  }
  float ndr = nd[row]; float bb = b3[c];
  hout[(size_t)row*16+c] = aa*ndr + bb;
  h2  [(size_t)row*16+c] = ab*ndr + bb;
}

// ---------------- GC3 mult (bf16 input, fused over 2*NN rows) ----------------
__global__ __launch_bounds__(256) void k_gemm3(const unsigned short* __restrict__ o, const float* __restrict__ W3,
     const float* __restrict__ ns, unsigned short* __restrict__ th, int nrows)
{
  __shared__ float Ws[128*16];
  int t = threadIdx.x;
  for (int i=t;i<2048;i+=256) Ws[i]=W3[i];
  __syncthreads();
  int row = blockIdx.x*16 + (t>>4);
  int c = t & 15;
  if (row >= nrows) return;
  const unsigned short* p = o + (size_t)row*128;
  float acc=0.f;
  #pragma unroll
  for (int s8=0;s8<16;s8++){
    bf16x8 v = *(const bf16x8*)(p + s8*8);
    #pragma unroll
    for (int i=0;i<8;i++) acc += bf2f((unsigned short)v[i]) * Ws[(s8*8+i)*16 + c];
  }
  int sidx = row >= NN ? row - NN : row;
  th[(size_t)row*16+c] = f2bf(acc*ns[sidx]);
}

// ---------------- ret_h / ret_ha ----------------
__global__ __launch_bounds__(256) void k_ret_h(const float* __restrict__ h1, const float* __restrict__ h2,
  const float* __restrict__ Wdh, const float* __restrict__ bdh,
  float* __restrict__ rh, float* __restrict__ rha)
{
  __shared__ float Ws[256];
  int t = threadIdx.x;
  if (t<256) Ws[t]=Wdh[t];
  __syncthreads();
  int n = blockIdx.x*256 + t;
  if (n>=NN) return;
  float e1[16], e2[16];
  float s1=0.f, s2=0.f;
  const float* p1 = h1 + (size_t)n*16;
  const float* p2 = h2 + (size_t)n*16;
  #pragma unroll
  for (int i=0;i<16;i++){
    e1[i]=fmaxf(p1[i],0.f); s1+=e1[i]*e1[i];
    e2[i]=fmaxf(p2[i],0.f); s2+=e2[i]*e2[i];
  }
  float r1 = 1.0f/fmaxf(sqrtf(s1),1e-12f);
  float r2 = 1.0f/fmaxf(sqrtf(s2),1e-12f);
  float g1[16], g2[16];
  #pragma unroll
  for (int i=0;i<16;i++){ g1[i]=sigm(e1[i]*r1); g2[i]=sigm(e2[i]*r2); }
  float q00=0.f,q01=0.f,q10=0.f,q11=0.f;
  #pragma unroll
  for (int d=0; d<16; d++){
    float vh1=0.f, vh2=0.f;
    #pragma unroll
    for (int e=0;e<16;e++){ vh1 += Ws[d*16+e]*g1[e]; vh2 += Ws[d*16+e]*g2[e]; }
    q00 += e1[d]*vh1; q01 += e2[d]*vh1;
    q10 += e2[d]*vh2; q11 += e1[d]*vh2;
  }
  float bb = bdh[0];
  rh [(size_t)n*2+0]=q00+bb; rh [(size_t)n*2+1]=q01+bb;
  rha[(size_t)n*2+0]=q10+bb; rha[(size_t)n*2+1]=q11+bb;
}

// ---------------- launch ----------------
extern "C" void kernel_launch(void* const* d_in, const int* in_sizes, int n_in,
                              void* d_out, int out_size, void* d_ws, size_t ws_size,
                              hipStream_t stream){
  const float* x   = (const float*)d_in[0];
  const float* W1  = (const float*)d_in[1];
  const float* b1  = (const float*)d_in[2];
  const float* W2  = (const float*)d_in[3];
  const float* b2  = (const float*)d_in[4];
  const float* W3  = (const float*)d_in[5];
  const float* b3  = (const float*)d_in[6];
  const float* Wdo = (const float*)d_in[7];
  const float* bdo = (const float*)d_in[8];
  const float* Wdh = (const float*)d_in[9];
  const float* bdh = (const float*)d_in[10];
  const int* ei    = (const int*)d_in[11];
  const int* perm  = (const int*)d_in[12];
  const int* esrc = ei;
  const int* edst = ei + EE;

  char* ws = (char*)d_ws;
  size_t off = 0;
  auto alloc = [&](size_t bytes)->void*{ void* p = ws + off; off += (bytes + 255) & ~(size_t)255; return p; };
  unsigned short* zs = (unsigned short*)alloc((size_t)NN*128*2);   // messages enc1 / t1
  unsigned short* zp = (unsigned short*)alloc((size_t)NN*128*2);   // messages enc2 / t2 (contiguous)
  unsigned short* ob = (unsigned short*)alloc((size_t)2*NN*128*2); // o (bf16), enc1 rows 0..NN-1, enc2 rows NN..
  unsigned short* th = (unsigned short*)alloc((size_t)2*NN*16*2);
  float* h2 = (float*)alloc((size_t)NN*16*4);
  int* deg = (int*)alloc((size_t)2*NN*4);
  int* dout_ = deg; int* din_ = deg + NN;
  float* ns = (float*)alloc((size_t)NN*4);
  float* nd = (float*)alloc((size_t)NN*4);
  int* inv  = (int*)alloc((size_t)NN*4);
  float* rn = (float*)alloc((size_t)2*NN*4);
  int* cursor = (int*)alloc((size_t)NN*4);
  int* row_ptr = (int*)alloc((size_t)(NN+1)*4);
  int* colx = (int*)alloc((size_t)EE*4);
  int* chunk = (int*)alloc((size_t)NN*4);
  int* bsum = (int*)alloc((size_t)SCB*4);
  int* bpre = (int*)alloc((size_t)SCB*4);
  unsigned short* W1T = (unsigned short*)alloc((size_t)1024*128*2);
  unsigned short* W2T = (unsigned short*)alloc((size_t)128*128*2);
  unsigned short* WdoB = (unsigned short*)alloc((size_t)128*128*2);

  float* out_h   = (float*)d_out;
  float* out_ro  = out_h  + (size_t)NN*16;
  float* out_rh  = out_ro + (size_t)NN*2;
  float* out_roa = out_rh + (size_t)NN*2;
  float* out_rha = out_roa+ (size_t)NN*2;

  hipMemsetAsync(deg, 0, (size_t)2*NN*4, stream);
  // weight preconversion -> chunked layout
  k_wcvt<<<(1024*128+255)/256,256,0,stream>>>(W1, W1T, 1024, 1);
  k_wcvt<<<(128*128+255)/256,256,0,stream>>>(W2, W2T, 128, 1);
  k_wcvt<<<(128*128+255)/256,256,0,stream>>>(Wdo, WdoB, 128, 0);
  // CSR build
  k_deg <<<EE/256, 256, 0, stream>>>(esrc, edst, dout_, din_);
  k_norminv<<<(NN+255)/256, 256, 0, stream>>>(dout_, din_, perm, ns, nd, inv);
  k_scan1<<<SCB, 1024, 0, stream>>>(din_, chunk, bsum);
  k_scan2<<<1, 128, 0, stream>>>(bsum, bpre, row_ptr);
  k_scan3<<<(NN+255)/256, 256, 0, stream>>>(din_, chunk, bpre, row_ptr, cursor);
  k_fill<<<EE/256, 256, 0, stream>>>(esrc, edst, cursor, colx);

  int gb1 = (NN + 63)/64;
  int gb2 = (2*NN)/64;
  // GC1: z = x@W1 once; epilogue writes zs and zp (scatter by inv-perm)
  k_gemmA<1024,0,0,float><<<gb1,256,0,stream>>>(x, W1T, zs, zp, ns, inv, nullptr, NN, nullptr, nullptr);
  k_agg128<false><<<(NN+3)/4,256,0,stream>>>(zs, zp, row_ptr, colx, nd, b1, ob, nullptr);
  // GC2 fused over both encodes (bf16 A), +residual agg (fuses rn)
  k_gemmA<128,0,1,unsigned short><<<gb2,256,0,stream>>>(ob, W2T, zs, nullptr, ns, nullptr, nullptr, 2*NN, nullptr, nullptr);
  k_agg128<true><<<(NN+3)/4,256,0,stream>>>(zs, zp, row_ptr, colx, nd, b2, ob, rn);
  // GC3 fused
  k_gemm3<<<(2*NN+15)/16,256,0,stream>>>(ob, W3, ns, th, 2*NN);
  k_agg16<<<(NN+15)/16,256,0,stream>>>(th, th + (size_t)NN*16, row_ptr, colx, nd, b3, out_h, h2);
  // discriminator (o-path): v = sigm(relu(o)*rn) @ Wdo^T with fused ret_o epilogue
  k_gemmA<128,1,3,unsigned short><<<gb2,256,0,stream>>>(ob, WdoB, nullptr, nullptr, bdo, nullptr, rn, 2*NN, out_ro, out_roa);
  // discriminator (h-path)
  k_ret_h<<<(NN+255)/256,256,0,stream>>>(out_h, h2, Wdh, bdh, out_rh, out_rha);
}

// Round 6
// 758.180 us; speedup vs baseline: 1.5855x; 1.0831x over previous
//
#include <hip/hip_runtime.h>
#include <math.h>

#define NN 100000
#define EE 1600000
#define SCB 98  // ceil(NN/1024)

typedef __attribute__((ext_vector_type(8))) short bf16x8;
typedef __attribute__((ext_vector_type(4))) short bf16x4;
typedef __attribute__((ext_vector_type(4))) float f32x4;

__device__ __forceinline__ unsigned short f2bf(float x){
  union { float f; unsigned u; } v; v.f = x;
  unsigned r = v.u + 0x7FFFu + ((v.u >> 16) & 1u);
  return (unsigned short)(r >> 16);
}
__device__ __forceinline__ float bf2f(unsigned short h){
  union { unsigned u; float f; } v; v.u = ((unsigned)h) << 16; return v.f;
}
__device__ __forceinline__ float sigm(float x){ return 1.0f/(1.0f+__expf(-x)); }

// ---------------- degree ----------------
__global__ __launch_bounds__(256) void k_deg(const int* __restrict__ src, const int* __restrict__ dst,
                      int* __restrict__ dout, int* __restrict__ din){
  int e = blockIdx.x*256 + threadIdx.x;
  if (e < EE){ atomicAdd(&dout[src[e]],1); atomicAdd(&din[dst[e]],1); }
}

// ---------------- parallel scan (3 phases; phase3 fused with norm/inv) ----------------
__global__ __launch_bounds__(1024) void k_scan1(const int* __restrict__ din, int* __restrict__ chunk,
                        int* __restrict__ bsum){
  __shared__ int wsum[16];
  int t = threadIdx.x, lane = t & 63, w = t >> 6;
  int i = blockIdx.x*1024 + t;
  int v = (i < NN) ? din[i] : 0;
  int x = v;
  #pragma unroll
  for (int off=1; off<64; off<<=1){
    int y = __shfl_up(x, off);
    if (lane>=off) x += y;
  }
  if (lane==63) wsum[w] = x;
  __syncthreads();
  int pre = 0;
  #pragma unroll
  for (int j=0;j<16;j++) if (j<w) pre += wsum[j];
  int incl = x + pre;
  if (i < NN) chunk[i] = incl;
  if (t == 1023) bsum[blockIdx.x] = incl;
}

__global__ __launch_bounds__(128) void k_scan2(const int* __restrict__ bsum, int* __restrict__ bpre,
                       int* __restrict__ row_ptr){
  __shared__ int w0tot;
  int t = threadIdx.x, lane = t & 63, w = t >> 6;
  int v = (t < SCB) ? bsum[t] : 0;
  int x = v;
  #pragma unroll
  for (int off=1; off<64; off<<=1){
    int y = __shfl_up(x, off);
    if (lane>=off) x += y;
  }
  if (w==0 && lane==63) w0tot = x;
  __syncthreads();
  int incl = x + (w ? w0tot : 0);
  if (t < SCB) bpre[t] = incl - v;
  if (t == 0) row_ptr[0] = 0;
}

__global__ __launch_bounds__(256) void k_scan3(const int* __restrict__ din, const int* __restrict__ chunk,
                       const int* __restrict__ bpre, const int* __restrict__ dout,
                       const int* __restrict__ perm,
                       int* __restrict__ row_ptr, int* __restrict__ cursor,
                       float* __restrict__ ns, float* __restrict__ nd, int* __restrict__ inv){
  int i = blockIdx.x*256 + threadIdx.x;
  if (i < NN){
    int d = din[i];
    int val = chunk[i] + bpre[i>>10];
    row_ptr[i+1] = val;
    cursor[i] = val - d;
    ns[i] = rsqrtf((float)max(dout[i],1));
    nd[i] = rsqrtf((float)max(d,1));
    inv[perm[i]] = i;
  }
}

__global__ __launch_bounds__(256) void k_fill(const int* __restrict__ src, const int* __restrict__ dst,
                       int* __restrict__ cursor, int* __restrict__ col){
  int e = blockIdx.x*256+threadIdx.x;
  if (e<EE){ int pos = atomicAdd(&cursor[dst[e]],1); col[pos] = src[e]; }
}

// ---------------- weight convert (all weights, one kernel) ----------------
// chunked layout: [chunk(64k)][col][k-in-chunk]; W3c: [col(16)][k(128)]
__global__ __launch_bounds__(256) void k_wcvt_all(
  const float* __restrict__ W1, const float* __restrict__ W2,
  const float* __restrict__ Wdo, const float* __restrict__ W3,
  unsigned short* __restrict__ W1T, unsigned short* __restrict__ W2T,
  unsigned short* __restrict__ WdoB, unsigned short* __restrict__ W3c)
{
  int i = blockIdx.x*256 + threadIdx.x;
  if (i < 131072){
    int c = i>>13, r = i&8191, col = r>>6, k = c*64 + (r&63);
    W1T[i] = f2bf(W1[(size_t)k*128 + col]);
  } else if (i < 147456){
    int j = i-131072;
    int c = j>>13, r = j&8191, col = r>>6, k = c*64 + (r&63);
    W2T[j] = f2bf(W2[(size_t)k*128 + col]);
  } else if (i < 163840){
    int j = i-147456;
    int c = j>>13, r = j&8191, col = r>>6, k = c*64 + (r&63);
    WdoB[j] = f2bf(Wdo[(size_t)col*128 + k]);   // B = Wdo^T
  } else if (i < 165888){
    int j = i-163840;
    int col = j>>7, k = j&127;
    W3c[j] = f2bf(W3[(size_t)k*16 + col]);
  }
}

// ---------------- A-fragment holders ----------------
struct ARF { float4 a, b; };
struct ARU { bf16x8 a; };
__device__ __forceinline__ void aload(ARF& r, const float* p){
  r.a = *(const float4*)p; r.b = *(const float4*)(p+4);
}
__device__ __forceinline__ void aload(ARU& r, const unsigned short* p){
  r.a = *(const bf16x8*)p;
}
template<int IM>
__device__ __forceinline__ bf16x8 aconv(const ARF& r, float rs){
  float av[8] = {r.a.x,r.a.y,r.a.z,r.a.w,r.b.x,r.b.y,r.b.z,r.b.w};
  if constexpr (IM==1){
    #pragma unroll
    for (int i=0;i<8;i++) av[i] = sigm(fmaxf(av[i],0.0f)*rs);
  }
  bf16x8 o;
  #pragma unroll
  for (int i=0;i<8;i++) o[i] = (short)f2bf(av[i]);
  return o;
}
template<int IM>
__device__ __forceinline__ bf16x8 aconv(const ARU& r, float rs){
  if constexpr (IM==0) return r.a;
  else {
    bf16x8 o;
    #pragma unroll
    for (int i=0;i<8;i++){
      float v = sigm(fmaxf(bf2f((unsigned short)r.a[i]),0.0f)*rs);
      o[i] = (short)f2bf(v);
    }
    return o;
  }
}
__device__ __forceinline__ bf16x8 araw(const ARU& r){ return r.a; }
__device__ __forceinline__ bf16x8 araw(const ARF& r){
  bf16x8 o;
  float av[8] = {r.a.x,r.a.y,r.a.z,r.a.w,r.b.x,r.b.y,r.b.z,r.b.w};
  #pragma unroll
  for (int i=0;i<8;i++) o[i] = (short)f2bf(av[i]);
  return o;
}
template<typename T> struct ARofT;
template<> struct ARofT<float>{ using type = ARF; };
template<> struct ARofT<unsigned short>{ using type = ARU; };

// ---------------- MFMA GEMM ----------------
// A direct-to-reg 2-chunk prefetch; B reg-staged to XOR-swizzled LDS (32KB dbuf).
// Iteration cc: [A-loads(cc+2)] [MFMA cc] [ds_write w(cc+1); barrier; B-loads(cc+2)]
// (B-load for cc+2 AFTER the ds_write of cc+1 — w regs must not be clobbered before
//  the write consumes them; this was the round-5 bug.)
// IN_MODE: 0 plain ; 1 sigmoid(relu(a)*rn[row])
// OUT_MODE: 0 z/zp scatter into interleaved z[N][2][128]
//           1 z[row interleaved] = v*scale[row%NN]
//           3 fused: th=(o@W3)*ns (extra MFMA on raw A) + discriminator dots -> ro/roa
template<int KDIM, int IN_MODE, int OUT_MODE, typename AT>
__global__ __launch_bounds__(256,4) void k_gemmA(
    const AT* __restrict__ A, const unsigned short* __restrict__ Wc,
    unsigned short* __restrict__ out0,
    const float* __restrict__ scale, const int* __restrict__ inv,
    const float* __restrict__ rn, int nrows,
    float* __restrict__ ro, float* __restrict__ roa,
    const unsigned short* __restrict__ W3c, const float* __restrict__ ns2,
    unsigned short* __restrict__ th)
{
  constexpr int NC = KDIM/64;
  __shared__ __align__(16) unsigned short Bs[2*128*64];
  __shared__ __align__(16) unsigned short W3s[OUT_MODE==3 ? 16*128 : 16];
  int t = threadIdx.x, wave = t>>6, lane = t&63;
  int row0 = blockIdx.x*64;
  int arow = row0 + wave*16 + (lane&15);
  int kof = (lane>>4)*8;
  int arow_c = min(arow, nrows-1);
  const AT* ap = A + (size_t)arow_c*KDIM + kof;
  float rscale = 1.0f;
  if constexpr (IN_MODE==1) rscale = rn[arow_c];

  int scol = t>>3;                      // col within j-piece group (col = j*32+scol)
  int sw = ((t&7) ^ (scol&7))<<3;       // swizzled slot offset (shorts)

  unsigned short* b0 = &Bs[0];
  unsigned short* b1 = &Bs[128*64];
  const unsigned short* bcur = b0; unsigned short* bnxt = b1;

  f32x4 acc[8] = {};
  f32x4 acc2 = {};
  typename ARofT<AT>::type A0a{},A0b{},A1a{},A1b{},A2a{},A2b{};
  bf16x8 w0{},w1{},w2{},w3{};

  // prologue: stage chunk0 -> LDS, W3 -> LDS, load A chunks 0,1, issue B chunk1
  {
    const unsigned short* gp = Wc + (size_t)t*8;
    bf16x8 t0 = *(const bf16x8*)(gp);
    bf16x8 t1 = *(const bf16x8*)(gp+2048);
    bf16x8 t2 = *(const bf16x8*)(gp+4096);
    bf16x8 t3 = *(const bf16x8*)(gp+6144);
    *(bf16x8*)&b0[(0*32+scol)*64 + sw] = t0;
    *(bf16x8*)&b0[(1*32+scol)*64 + sw] = t1;
    *(bf16x8*)&b0[(2*32+scol)*64 + sw] = t2;
    *(bf16x8*)&b0[(3*32+scol)*64 + sw] = t3;
  }
  if constexpr (OUT_MODE==3){
    int wc = t>>4, wsl = t&15;
    bf16x8 v = *(const bf16x8*)(W3c + wc*128 + wsl*8);
    *(bf16x8*)&W3s[wc*128 + ((wsl ^ (wc&7))<<3)] = v;
  }
  aload(A0a, ap); aload(A0b, ap+32);
  if (NC>1){
    const unsigned short* gp = Wc + 8192 + (size_t)t*8;
    w0 = *(const bf16x8*)(gp);
    w1 = *(const bf16x8*)(gp+2048);
    w2 = *(const bf16x8*)(gp+4096);
    w3 = *(const bf16x8*)(gp+6144);
    aload(A1a, ap+64); aload(A1b, ap+96);
  }
  __syncthreads();

  int slot0 = lane>>4;      // step0 slot; step1 = slot0+4
  int c = lane & 15;
  #pragma unroll
  for (int cc=0; cc<NC; ++cc){
    // A prefetch (2 chunks ahead); issued after w(cc+1) so the ds_write's
    // in-order vmcnt wait does NOT force these to retire early
    if (cc+2 < NC){
      aload(A2a, ap + (cc+2)*64);
      aload(A2b, ap + (cc+2)*64 + 32);
    }
    // step 0 (k 0..31 of chunk)
    {
      bf16x8 af = aconv<IN_MODE>(A0a, rscale);
      #pragma unroll
      for (int j=0;j<8;j++){
        int cj = j*16 + c;
        bf16x8 b = *(const bf16x8*)&bcur[cj*64 + ((slot0 ^ (cj&7))<<3)];
        acc[j] = __builtin_amdgcn_mfma_f32_16x16x32_bf16(af, b, acc[j], 0, 0, 0);
      }
      if constexpr (OUT_MODE==3){
        int sl = cc*8 + slot0;
        bf16x8 b = *(const bf16x8*)&W3s[c*128 + ((sl ^ (c&7))<<3)];
        acc2 = __builtin_amdgcn_mfma_f32_16x16x32_bf16(araw(A0a), b, acc2, 0, 0, 0);
      }
    }
    // step 1 (k 32..63)
    {
      bf16x8 af = aconv<IN_MODE>(A0b, rscale);
      #pragma unroll
      for (int j=0;j<8;j++){
        int cj = j*16 + c;
        bf16x8 b = *(const bf16x8*)&bcur[cj*64 + (((slot0+4) ^ (cj&7))<<3)];
        acc[j] = __builtin_amdgcn_mfma_f32_16x16x32_bf16(af, b, acc[j], 0, 0, 0);
      }
      if constexpr (OUT_MODE==3){
        int sl = cc*8 + 4 + slot0;
        bf16x8 b = *(const bf16x8*)&W3s[c*128 + ((sl ^ (c&7))<<3)];
        acc2 = __builtin_amdgcn_mfma_f32_16x16x32_bf16(araw(A0b), b, acc2, 0, 0, 0);
      }
    }
    if (cc+1 < NC){
      // write chunk cc+1 (held in w since last iteration / prologue)
      *(bf16x8*)&bnxt[(0*32+scol)*64 + sw] = w0;
      *(bf16x8*)&bnxt[(1*32+scol)*64 + sw] = w1;
      *(bf16x8*)&bnxt[(2*32+scol)*64 + sw] = w2;
      *(bf16x8*)&bnxt[(3*32+scol)*64 + sw] = w3;
      __syncthreads();
      const unsigned short* tmp = bcur; bcur = bnxt; bnxt = (unsigned short*)tmp;
      // now safe to issue chunk cc+2's B loads into w
      if (cc+2 < NC){
        const unsigned short* gp = Wc + (size_t)(cc+2)*8192 + (size_t)t*8;
        w0 = *(const bf16x8*)(gp);
        w1 = *(const bf16x8*)(gp+2048);
        w2 = *(const bf16x8*)(gp+4096);
        w3 = *(const bf16x8*)(gp+6144);
      }
    }
    A0a=A1a; A0b=A1b; A1a=A2a; A1b=A2b;
  }

  if constexpr (OUT_MODE==3){
    // th = (o @ W3) * ns
    #pragma unroll
    for (int r=0;r<4;r++){
      int row = row0 + wave*16 + (lane>>4)*4 + r;
      int sidx = row>=NN ? row-NN : row;
      float v = acc2[r]*ns2[sidx];
      size_t tof = row<NN ? (size_t)row*32 + c : (size_t)(row-NN)*32 + 16 + c;
      th[tof] = f2bf(v);
    }
    // discriminator dots: restage o_same / o_other rows into LDS (swizzled)
    __syncthreads();
    unsigned short* Os = &Bs[0];
    unsigned short* Oo = &Bs[8192];
    for (int p=t; p<2048; p+=256){
      int r = (p>>4)&63, seg = p&15;
      int row = row0 + r;
      int srcrow = (p<1024) ? row : (row<NN ? row+NN : row-NN);
      unsigned short* dst = (p<1024) ? Os : Oo;
      *(bf16x8*)&dst[r*128 + ((seg ^ (r&7))<<3)] = *(const bf16x8*)&A[(size_t)srcrow*128 + seg*8];
    }
    __syncthreads();
    float bb = scale[0];
    #pragma unroll
    for (int r=0;r<4;r++){
      int lr = wave*16 + (lane>>4)*4 + r;
      float dsame=0.f, doth=0.f;
      #pragma unroll
      for (int j=0;j<8;j++){
        float v = acc[j][r];
        int colj = j*16 + c;
        int idx = lr*128 + (((colj>>3) ^ (lr&7))<<3) + (colj&7);
        dsame += fmaxf(bf2f(Os[idx]),0.f)*v;
        doth  += fmaxf(bf2f(Oo[idx]),0.f)*v;
      }
      #pragma unroll
      for (int off=1; off<16; off<<=1){
        dsame += __shfl_xor(dsame, off);
        doth  += __shfl_xor(doth, off);
      }
      if (c==0){
        int row = row0 + lr;
        if (row < NN){
          ro[(size_t)row*2+0] = dsame + bb;
          ro[(size_t)row*2+1] = doth + bb;
        } else {
          int m = row - NN;
          roa[(size_t)m*2+0] = dsame + bb;
          roa[(size_t)m*2+1] = doth + bb;
        }
      }
    }
  } else {
    // C/D: col=lane&15, row=(lane>>4)*4+reg
    int rbase = row0 + wave*16 + (lane>>4)*4;
    #pragma unroll
    for (int j=0;j<8;j++){
      int colx = j*16 + c;
      #pragma unroll
      for (int r=0;r<4;r++){
        int row = rbase + r;
        if (row < nrows){
          float v = acc[j][r];
          if constexpr (OUT_MODE==0){
            out0[(size_t)row*256 + colx] = f2bf(v * scale[row]);
            int ir = inv[row];
            out0[(size_t)ir*256 + 128 + colx] = f2bf(v * scale[ir]);
          } else {
            int sidx = row >= NN ? row - NN : row;
            size_t zof = row < NN ? (size_t)row*256 + colx : (size_t)(row-NN)*256 + 128 + colx;
            out0[zof] = f2bf(v * scale[sidx]);
          }
        }
      }
    }
  }
}

// ---------------- CSR aggregation, width 128, interleaved z[N][2][128] ----------------
// wave per row; 2 edge-slots x 32 lanes (512B contiguous per edge); 2-deep col lookahead
template<bool RESID>
__global__ __launch_bounds__(256) void k_agg128(
  const unsigned short* __restrict__ z,
  const int* __restrict__ row_ptr, const int* __restrict__ col,
  const float* __restrict__ nd, const float* __restrict__ bias,
  unsigned short* __restrict__ ob, float* __restrict__ rn)
{
  int wave = threadIdx.x>>6, lane = threadIdx.x&63;
  int row = blockIdx.x*4 + wave;
  if (row >= NN) return;
  int s = row_ptr[row], e = row_ptr[row+1];
  int es = lane>>5;
  int half = (lane>>4)&1;
  int c8 = (lane&15)*8;
  size_t lof = (size_t)half*128 + c8;
  float acc[8] = {};
  int i = s + es;
  int sc0 = (i < e) ? col[i] : -1;
  int sc1 = (i+2 < e) ? col[i+2] : -1;
  while (sc0 >= 0){
    bf16x8 u0 = *(const bf16x8*)(z + (size_t)sc0*256 + lof);
    bf16x8 u1 = {};
    bool h1 = sc1 >= 0;
    if (h1) u1 = *(const bf16x8*)(z + (size_t)sc1*256 + lof);
    int sc2 = (i+4 < e) ? col[i+4] : -1;
    int sc3 = (i+6 < e) ? col[i+6] : -1;
    #pragma unroll
    for (int j=0;j<8;j++) acc[j] += bf2f((unsigned short)u0[j]);
    if (h1){
      #pragma unroll
      for (int j=0;j<8;j++) acc[j] += bf2f((unsigned short)u1[j]);
    }
    sc0 = sc2; sc1 = sc3; i += 4;
  }
  #pragma unroll
  for (int j=0;j<8;j++) acc[j] += __shfl_down(acc[j], 32);
  if (lane < 32){
    float ndr = nd[row];
    size_t oof = half ? (size_t)(NN+row)*128 + c8 : (size_t)row*128 + c8;
    float ra[8];
    #pragma unroll
    for (int j=0;j<8;j++) ra[j] = acc[j]*ndr + bias[c8+j];
    if constexpr (RESID){
      bf16x8 pv = *(const bf16x8*)(ob + oof);
      #pragma unroll
      for (int j=0;j<8;j++) ra[j] += bf2f((unsigned short)pv[j]);
    }
    bf16x8 wv;
    #pragma unroll
    for (int j=0;j<8;j++) wv[j] = (short)f2bf(ra[j]);
    *(bf16x8*)(ob + oof) = wv;
    if constexpr (RESID){
      float sa = 0.f;
      #pragma unroll
      for (int j=0;j<8;j++){ float x1 = fmaxf(ra[j],0.f); sa += x1*x1; }
      sa += __shfl_down(sa, 8);
      sa += __shfl_down(sa, 4);
      sa += __shfl_down(sa, 2);
      sa += __shfl_down(sa, 1);
      if ((lane&15)==0) rn[half ? NN+row : row] = 1.0f/fmaxf(sqrtf(sa),1e-12f);
    }
  }
}

// ---------------- width-16 aggregation (GC3), th[N][2][16], 8 edge-slots/wave ----------------
__global__ __launch_bounds__(256) void k_agg16(
  const unsigned short* __restrict__ th,
  const int* __restrict__ row_ptr, const int* __restrict__ col,
  const float* __restrict__ nd, const float* __restrict__ b3,
  float* __restrict__ hout, float* __restrict__ h2)
{
  int wave = threadIdx.x>>6, lane = threadIdx.x&63;
  int row = blockIdx.x*4 + wave;
  if (row >= NN) return;
  int s = row_ptr[row], e = row_ptr[row+1];
  int es = lane>>3, l8 = lane&7;
  float a4[4] = {};
  int i = s + es;
  int sc0 = (i<e)? col[i] : -1;
  int sc1 = (i+8<e)? col[i+8] : -1;
  while (sc0 >= 0){
    bf16x4 u0 = *(const bf16x4*)(th + (size_t)sc0*32 + l8*4);
    bf16x4 u1 = {};
    bool h1 = sc1>=0;
    if (h1) u1 = *(const bf16x4*)(th + (size_t)sc1*32 + l8*4);
    int sc2 = (i+16<e)? col[i+16] : -1;
    int sc3 = (i+24<e)? col[i+24] : -1;
    #pragma unroll
    for (int j=0;j<4;j++) a4[j] += bf2f((unsigned short)u0[j]);
    if (h1){
      #pragma unroll
      for (int j=0;j<4;j++) a4[j] += bf2f((unsigned short)u1[j]);
    }
    sc0=sc2; sc1=sc3; i += 16;
  }
  #pragma unroll
  for (int j=0;j<4;j++){
    a4[j] += __shfl_down(a4[j], 32);
    a4[j] += __shfl_down(a4[j], 16);
    a4[j] += __shfl_down(a4[j], 8);
  }
  if (lane < 8){
    float ndr = nd[row];
    int half = l8>>2, c0 = (l8&3)*4;
    float4 r;
    r.x = a4[0]*ndr + b3[c0+0];
    r.y = a4[1]*ndr + b3[c0+1];
    r.z = a4[2]*ndr + b3[c0+2];
    r.w = a4[3]*ndr + b3[c0+3];
    if (half==0) *(float4*)&hout[(size_t)row*16 + c0] = r;
    else         *(float4*)&h2  [(size_t)row*16 + c0] = r;
  }
}

// ---------------- ret_h / ret_ha ----------------
__global__ __launch_bounds__(256) void k_ret_h(const float* __restrict__ h1, const float* __restrict__ h2,
  const float* __restrict__ Wdh, const float* __restrict__ bdh,
  float* __restrict__ rh, float* __restrict__ rha)
{
  __shared__ float Ws[256];
  int t = threadIdx.x;
  if (t<256) Ws[t]=Wdh[t];
  __syncthreads();
  int n = blockIdx.x*256 + t;
  if (n>=NN) return;
  float e1[16], e2[16];
  float s1=0.f, s2=0.f;
  const float* p1 = h1 + (size_t)n*16;
  const float* p2 = h2 + (size_t)n*16;
  #pragma unroll
  for (int i=0;i<16;i++){
    e1[i]=fmaxf(p1[i],0.f); s1+=e1[i]*e1[i];
    e2[i]=fmaxf(p2[i],0.f); s2+=e2[i]*e2[i];
  }
  float r1 = 1.0f/fmaxf(sqrtf(s1),1e-12f);
  float r2 = 1.0f/fmaxf(sqrtf(s2),1e-12f);
  float g1[16], g2[16];
  #pragma unroll
  for (int i=0;i<16;i++){ g1[i]=sigm(e1[i]*r1); g2[i]=sigm(e2[i]*r2); }
  float q00=0.f,q01=0.f,q10=0.f,q11=0.f;
  #pragma unroll
  for (int d=0; d<16; d++){
    float vh1=0.f, vh2=0.f;
    #pragma unroll
    for (int e=0;e<16;e++){ vh1 += Ws[d*16+e]*g1[e]; vh2 += Ws[d*16+e]*g2[e]; }
    q00 += e1[d]*vh1; q01 += e2[d]*vh1;
    q10 += e2[d]*vh2; q11 += e1[d]*vh2;
  }
  float bb = bdh[0];
  rh [(size_t)n*2+0]=q00+bb; rh [(size_t)n*2+1]=q01+bb;
  rha[(size_t)n*2+0]=q10+bb; rha[(size_t)n*2+1]=q11+bb;
}

// ---------------- launch ----------------
extern "C" void kernel_launch(void* const* d_in, const int* in_sizes, int n_in,
                              void* d_out, int out_size, void* d_ws, size_t ws_size,
                              hipStream_t stream){
  const float* x   = (const float*)d_in[0];
  const float* W1  = (const float*)d_in[1];
  const float* b1  = (const float*)d_in[2];
  const float* W2  = (const float*)d_in[3];
  const float* b2  = (const float*)d_in[4];
  const float* W3  = (const float*)d_in[5];
  const float* b3  = (const float*)d_in[6];
  const float* Wdo = (const float*)d_in[7];
  const float* bdo = (const float*)d_in[8];
  const float* Wdh = (const float*)d_in[9];
  const float* bdh = (const float*)d_in[10];
  const int* ei    = (const int*)d_in[11];
  const int* perm  = (const int*)d_in[12];
  const int* esrc = ei;
  const int* edst = ei + EE;

  char* ws = (char*)d_ws;
  size_t off = 0;
  auto alloc = [&](size_t bytes)->void*{ void* p = ws + off; off += (bytes + 255) & ~(size_t)255; return p; };
  unsigned short* z  = (unsigned short*)alloc((size_t)NN*256*2);   // messages interleaved [N][2][128]
  unsigned short* ob = (unsigned short*)alloc((size_t)2*NN*128*2); // o bf16: rows 0..NN-1 enc1, NN.. enc2
  unsigned short* th = (unsigned short*)alloc((size_t)NN*32*2);    // GC3 messages interleaved [N][2][16]
  float* h2 = (float*)alloc((size_t)NN*16*4);
  int* deg = (int*)alloc((size_t)2*NN*4);
  int* dout_ = deg; int* din_ = deg + NN;
  float* ns = (float*)alloc((size_t)NN*4);
  float* nd = (float*)alloc((size_t)NN*4);
  int* inv  = (int*)alloc((size_t)NN*4);
  float* rn = (float*)alloc((size_t)2*NN*4);
  int* cursor = (int*)alloc((size_t)NN*4);
  int* row_ptr = (int*)alloc((size_t)(NN+1)*4);
  int* colx = (int*)alloc((size_t)EE*4);
  int* chunk = (int*)alloc((size_t)NN*4);
  int* bsum = (int*)alloc((size_t)SCB*4);
  int* bpre = (int*)alloc((size_t)SCB*4);
  unsigned short* W1T = (unsigned short*)alloc((size_t)1024*128*2);
  unsigned short* W2T = (unsigned short*)alloc((size_t)128*128*2);
  unsigned short* WdoB = (unsigned short*)alloc((size_t)128*128*2);
  unsigned short* W3c = (unsigned short*)alloc((size_t)16*128*2);

  float* out_h   = (float*)d_out;
  float* out_ro  = out_h  + (size_t)NN*16;
  float* out_rh  = out_ro + (size_t)NN*2;
  float* out_roa = out_rh + (size_t)NN*2;
  float* out_rha = out_roa+ (size_t)NN*2;

  hipMemsetAsync(deg, 0, (size_t)2*NN*4, stream);
  k_wcvt_all<<<648,256,0,stream>>>(W1, W2, Wdo, W3, W1T, W2T, WdoB, W3c);
  k_deg <<<EE/256, 256, 0, stream>>>(esrc, edst, dout_, din_);
  k_scan1<<<SCB, 1024, 0, stream>>>(din_, chunk, bsum);
  k_scan2<<<1, 128, 0, stream>>>(bsum, bpre, row_ptr);
  k_scan3<<<(NN+255)/256, 256, 0, stream>>>(din_, chunk, bpre, dout_, perm, row_ptr, cursor, ns, nd, inv);
  k_fill<<<EE/256, 256, 0, stream>>>(esrc, edst, cursor, colx);

  int gb1 = (NN + 63)/64;
  int gb2 = (2*NN)/64;
  // GC1: z = x@W1 once; epilogue scatters both encodes into interleaved z
  k_gemmA<1024,0,0,float><<<gb1,256,0,stream>>>(x, W1T, z, ns, inv, nullptr, NN,
                                                nullptr, nullptr, nullptr, nullptr, nullptr);
  k_agg128<false><<<(NN+3)/4,256,0,stream>>>(z, row_ptr, colx, nd, b1, ob, nullptr);
  // GC2 fused over both encodes, +residual agg (fuses rn)
  k_gemmA<128,0,1,unsigned short><<<gb2,256,0,stream>>>(ob, W2T, z, ns, nullptr, nullptr, 2*NN,
                                                nullptr, nullptr, nullptr, nullptr, nullptr);
  k_agg128<true><<<(NN+3)/4,256,0,stream>>>(z, row_ptr, colx, nd, b2, ob, rn);
  // disc GEMM + fused GC3-mult (th) + fused ret_o epilogue
  k_gemmA<128,1,3,unsigned short><<<gb2,256,0,stream>>>(ob, WdoB, nullptr, bdo, nullptr, rn, 2*NN,
                                                out_ro, out_roa, W3c, ns, th);
  k_agg16<<<(NN+3)/4,256,0,stream>>>(th, row_ptr, colx, nd, b3, out_h, h2);
  k_ret_h<<<(NN+255)/256,256,0,stream>>>(out_h, h2, Wdh, bdh, out_rh, out_rha);
}

// Round 7
// 749.245 us; speedup vs baseline: 1.6044x; 1.0119x over previous
//
#include <hip/hip_runtime.h>
#include <math.h>

#define NN 100000
#define EE 1600000
#define SCB 98  // ceil(NN/1024)

typedef __attribute__((ext_vector_type(8))) short bf16x8;
typedef __attribute__((ext_vector_type(4))) short bf16x4;
typedef __attribute__((ext_vector_type(4))) float f32x4;

__device__ __forceinline__ unsigned short f2bf(float x){
  union { float f; unsigned u; } v; v.f = x;
  unsigned r = v.u + 0x7FFFu + ((v.u >> 16) & 1u);
  return (unsigned short)(r >> 16);
}
__device__ __forceinline__ float bf2f(unsigned short h){
  union { unsigned u; float f; } v; v.u = ((unsigned)h) << 16; return v.f;
}
__device__ __forceinline__ float sigm(float x){ return 1.0f/(1.0f+__expf(-x)); }

// light barrier: ds-ops drained, global loads stay in flight (T3/T4; guide §5)
__device__ __forceinline__ void barrier_lds_only(){
  asm volatile("s_waitcnt lgkmcnt(0)" ::: "memory");
  __builtin_amdgcn_s_barrier();
  __builtin_amdgcn_sched_barrier(0);
}

// ---------------- degree + weight convert (merged; independent work) ----------------
// chunked layout: [chunk(64k)][col][k-in-chunk]; W3c: [col(16)][k(128)]
__global__ __launch_bounds__(256) void k_deg_wcvt(const int* __restrict__ src, const int* __restrict__ dst,
                      int* __restrict__ dout, int* __restrict__ din,
                      const float* __restrict__ W1, const float* __restrict__ W2,
                      const float* __restrict__ Wdo, const float* __restrict__ W3,
                      unsigned short* __restrict__ W1T, unsigned short* __restrict__ W2T,
                      unsigned short* __restrict__ WdoB, unsigned short* __restrict__ W3c){
  int b = blockIdx.x;
  if (b < EE/256){
    int e = b*256 + threadIdx.x;
    atomicAdd(&dout[src[e]],1); atomicAdd(&din[dst[e]],1);
  } else {
    int i = (b - EE/256)*256 + threadIdx.x;
    if (i < 131072){
      int c = i>>13, r = i&8191, col = r>>6, k = c*64 + (r&63);
      W1T[i] = f2bf(W1[(size_t)k*128 + col]);
    } else if (i < 147456){
      int j = i-131072;
      int c = j>>13, r = j&8191, col = r>>6, k = c*64 + (r&63);
      W2T[j] = f2bf(W2[(size_t)k*128 + col]);
    } else if (i < 163840){
      int j = i-147456;
      int c = j>>13, r = j&8191, col = r>>6, k = c*64 + (r&63);
      WdoB[j] = f2bf(Wdo[(size_t)col*128 + k]);   // B = Wdo^T
    } else if (i < 165888){
      int j = i-163840;
      int col = j>>7, k = j&127;
      W3c[j] = f2bf(W3[(size_t)k*16 + col]);
    }
  }
}

// ---------------- parallel scan (3 phases; phase3 fused with norm/inv) ----------------
__global__ __launch_bounds__(1024) void k_scan1(const int* __restrict__ din, int* __restrict__ chunk,
                        int* __restrict__ bsum){
  __shared__ int wsum[16];
  int t = threadIdx.x, lane = t & 63, w = t >> 6;
  int i = blockIdx.x*1024 + t;
  int v = (i < NN) ? din[i] : 0;
  int x = v;
  #pragma unroll
  for (int off=1; off<64; off<<=1){
    int y = __shfl_up(x, off);
    if (lane>=off) x += y;
  }
  if (lane==63) wsum[w] = x;
  __syncthreads();
  int pre = 0;
  #pragma unroll
  for (int j=0;j<16;j++) if (j<w) pre += wsum[j];
  int incl = x + pre;
  if (i < NN) chunk[i] = incl;
  if (t == 1023) bsum[blockIdx.x] = incl;
}

__global__ __launch_bounds__(128) void k_scan2(const int* __restrict__ bsum, int* __restrict__ bpre,
                       int* __restrict__ row_ptr){
  __shared__ int w0tot;
  int t = threadIdx.x, lane = t & 63, w = t >> 6;
  int v = (t < SCB) ? bsum[t] : 0;
  int x = v;
  #pragma unroll
  for (int off=1; off<64; off<<=1){
    int y = __shfl_up(x, off);
    if (lane>=off) x += y;
  }
  if (w==0 && lane==63) w0tot = x;
  __syncthreads();
  int incl = x + (w ? w0tot : 0);
  if (t < SCB) bpre[t] = incl - v;
  if (t == 0) row_ptr[0] = 0;
}

__global__ __launch_bounds__(256) void k_scan3(const int* __restrict__ din, const int* __restrict__ chunk,
                       const int* __restrict__ bpre, const int* __restrict__ dout,
                       const int* __restrict__ perm,
                       int* __restrict__ row_ptr, int* __restrict__ cursor,
                       float* __restrict__ ns, float* __restrict__ nd, int* __restrict__ inv){
  int i = blockIdx.x*256 + threadIdx.x;
  if (i < NN){
    int d = din[i];
    int val = chunk[i] + bpre[i>>10];
    row_ptr[i+1] = val;
    cursor[i] = val - d;
    ns[i] = rsqrtf((float)max(dout[i],1));
    nd[i] = rsqrtf((float)max(d,1));
    inv[perm[i]] = i;
  }
}

__global__ __launch_bounds__(256) void k_fill(const int* __restrict__ src, const int* __restrict__ dst,
                       int* __restrict__ cursor, int* __restrict__ col){
  int e = blockIdx.x*256+threadIdx.x;
  if (e<EE){ int pos = atomicAdd(&cursor[dst[e]],1); col[pos] = src[e]; }
}

// ---------------- A-fragment holders ----------------
struct ARF { float4 a, b; };
struct ARU { bf16x8 a; };
__device__ __forceinline__ void aload(ARF& r, const float* p){
  r.a = *(const float4*)p; r.b = *(const float4*)(p+4);
}
__device__ __forceinline__ void aload(ARU& r, const unsigned short* p){
  r.a = *(const bf16x8*)p;
}
template<int IM>
__device__ __forceinline__ bf16x8 aconv(const ARF& r, float rs){
  float av[8] = {r.a.x,r.a.y,r.a.z,r.a.w,r.b.x,r.b.y,r.b.z,r.b.w};
  if constexpr (IM==1){
    #pragma unroll
    for (int i=0;i<8;i++) av[i] = sigm(fmaxf(av[i],0.0f)*rs);
  }
  bf16x8 o;
  #pragma unroll
  for (int i=0;i<8;i++) o[i] = (short)f2bf(av[i]);
  return o;
}
template<int IM>
__device__ __forceinline__ bf16x8 aconv(const ARU& r, float rs){
  if constexpr (IM==0) return r.a;
  else {
    bf16x8 o;
    #pragma unroll
    for (int i=0;i<8;i++){
      float v = sigm(fmaxf(bf2f((unsigned short)r.a[i]),0.0f)*rs);
      o[i] = (short)f2bf(v);
    }
    return o;
  }
}
__device__ __forceinline__ bf16x8 araw(const ARU& r){ return r.a; }
__device__ __forceinline__ bf16x8 araw(const ARF& r){
  bf16x8 o;
  float av[8] = {r.a.x,r.a.y,r.a.z,r.a.w,r.b.x,r.b.y,r.b.z,r.b.w};
  #pragma unroll
  for (int i=0;i<8;i++) o[i] = (short)f2bf(av[i]);
  return o;
}
template<typename T> struct ARofT;
template<> struct ARofT<float>{ using type = ARF; };
template<> struct ARofT<unsigned short>{ using type = ARU; };

// ---------------- MFMA GEMM ----------------
// A direct-to-reg 2-chunk prefetch; B reg-staged to XOR-swizzled LDS (32KB dbuf).
// In-loop barrier is lgkmcnt-only (raw s_barrier): the compiler's __syncthreads
// vmcnt(0) drain would retire the A prefetch every chunk (guide §5). ds_write's
// own operand wait is a counted vmcnt (w-loads older than A-prefetch loads).
// IN_MODE: 0 plain ; 1 sigmoid(relu(a)*rn[row])
// OUT_MODE: 0 z/zp scatter into interleaved z[N][2][128]
//           1 z[row interleaved] = v*scale[row%NN]
//           3 fused: th=(o@W3)*ns (extra MFMA on raw A) + discriminator dots -> ro/roa
template<int KDIM, int IN_MODE, int OUT_MODE, typename AT>
__global__ __launch_bounds__(256,4) void k_gemmA(
    const AT* __restrict__ A, const unsigned short* __restrict__ Wc,
    unsigned short* __restrict__ out0,
    const float* __restrict__ scale, const int* __restrict__ inv,
    const float* __restrict__ rn, int nrows,
    float* __restrict__ ro, float* __restrict__ roa,
    const unsigned short* __restrict__ W3c, const float* __restrict__ ns2,
    unsigned short* __restrict__ th)
{
  constexpr int NC = KDIM/64;
  __shared__ __align__(16) unsigned short Bs[2*128*64];
  __shared__ __align__(16) unsigned short W3s[OUT_MODE==3 ? 16*128 : 16];
  int t = threadIdx.x, wave = t>>6, lane = t&63;
  int row0 = blockIdx.x*64;
  int arow = row0 + wave*16 + (lane&15);
  int kof = (lane>>4)*8;
  int arow_c = min(arow, nrows-1);
  const AT* ap = A + (size_t)arow_c*KDIM + kof;
  float rscale = 1.0f;
  if constexpr (IN_MODE==1) rscale = rn[arow_c];

  int scol = t>>3;                      // col within j-piece group (col = j*32+scol)
  int sw = ((t&7) ^ (scol&7))<<3;       // swizzled slot offset (shorts)

  unsigned short* b0 = &Bs[0];
  unsigned short* b1 = &Bs[128*64];
  const unsigned short* bcur = b0; unsigned short* bnxt = b1;

  f32x4 acc[8] = {};
  f32x4 acc2 = {};
  typename ARofT<AT>::type A0a{},A0b{},A1a{},A1b{},A2a{},A2b{};
  bf16x8 w0{},w1{},w2{},w3{};

  // prologue: stage chunk0 -> LDS, W3 -> LDS, load A chunks 0,1, issue B chunk1
  {
    const unsigned short* gp = Wc + (size_t)t*8;
    bf16x8 t0 = *(const bf16x8*)(gp);
    bf16x8 t1 = *(const bf16x8*)(gp+2048);
    bf16x8 t2 = *(const bf16x8*)(gp+4096);
    bf16x8 t3 = *(const bf16x8*)(gp+6144);
    *(bf16x8*)&b0[(0*32+scol)*64 + sw] = t0;
    *(bf16x8*)&b0[(1*32+scol)*64 + sw] = t1;
    *(bf16x8*)&b0[(2*32+scol)*64 + sw] = t2;
    *(bf16x8*)&b0[(3*32+scol)*64 + sw] = t3;
  }
  if constexpr (OUT_MODE==3){
    int wc = t>>4, wsl = t&15;
    bf16x8 v = *(const bf16x8*)(W3c + wc*128 + wsl*8);
    *(bf16x8*)&W3s[wc*128 + ((wsl ^ (wc&7))<<3)] = v;
  }
  aload(A0a, ap); aload(A0b, ap+32);
  if (NC>1){
    const unsigned short* gp = Wc + 8192 + (size_t)t*8;
    w0 = *(const bf16x8*)(gp);
    w1 = *(const bf16x8*)(gp+2048);
    w2 = *(const bf16x8*)(gp+4096);
    w3 = *(const bf16x8*)(gp+6144);
    aload(A1a, ap+64); aload(A1b, ap+96);
  }
  __syncthreads();

  int slot0 = lane>>4;      // step0 slot; step1 = slot0+4
  int c = lane & 15;
  #pragma unroll
  for (int cc=0; cc<NC; ++cc){
    // A prefetch (2 chunks ahead); stays in flight across the light barrier
    if (cc+2 < NC){
      aload(A2a, ap + (cc+2)*64);
      aload(A2b, ap + (cc+2)*64 + 32);
    }
    // step 0 (k 0..31 of chunk)
    {
      bf16x8 af = aconv<IN_MODE>(A0a, rscale);
      #pragma unroll
      for (int j=0;j<8;j++){
        int cj = j*16 + c;
        bf16x8 b = *(const bf16x8*)&bcur[cj*64 + ((slot0 ^ (cj&7))<<3)];
        acc[j] = __builtin_amdgcn_mfma_f32_16x16x32_bf16(af, b, acc[j], 0, 0, 0);
      }
      if constexpr (OUT_MODE==3){
        int sl = cc*8 + slot0;
        bf16x8 b = *(const bf16x8*)&W3s[c*128 + ((sl ^ (c&7))<<3)];
        acc2 = __builtin_amdgcn_mfma_f32_16x16x32_bf16(araw(A0a), b, acc2, 0, 0, 0);
      }
    }
    // step 1 (k 32..63)
    {
      bf16x8 af = aconv<IN_MODE>(A0b, rscale);
      #pragma unroll
      for (int j=0;j<8;j++){
        int cj = j*16 + c;
        bf16x8 b = *(const bf16x8*)&bcur[cj*64 + (((slot0+4) ^ (cj&7))<<3)];
        acc[j] = __builtin_amdgcn_mfma_f32_16x16x32_bf16(af, b, acc[j], 0, 0, 0);
      }
      if constexpr (OUT_MODE==3){
        int sl = cc*8 + 4 + slot0;
        bf16x8 b = *(const bf16x8*)&W3s[c*128 + ((sl ^ (c&7))<<3)];
        acc2 = __builtin_amdgcn_mfma_f32_16x16x32_bf16(araw(A0b), b, acc2, 0, 0, 0);
      }
    }
    if (cc+1 < NC){
      // write chunk cc+1 (held in w since last iteration / prologue)
      *(bf16x8*)&bnxt[(0*32+scol)*64 + sw] = w0;
      *(bf16x8*)&bnxt[(1*32+scol)*64 + sw] = w1;
      *(bf16x8*)&bnxt[(2*32+scol)*64 + sw] = w2;
      *(bf16x8*)&bnxt[(3*32+scol)*64 + sw] = w3;
      barrier_lds_only();   // ds-drain only; A2 global loads stay outstanding
      const unsigned short* tmp = bcur; bcur = bnxt; bnxt = (unsigned short*)tmp;
      // now safe to issue chunk cc+2's B loads into w
      if (cc+2 < NC){
        const unsigned short* gp = Wc + (size_t)(cc+2)*8192 + (size_t)t*8;
        w0 = *(const bf16x8*)(gp);
        w1 = *(const bf16x8*)(gp+2048);
        w2 = *(const bf16x8*)(gp+4096);
        w3 = *(const bf16x8*)(gp+6144);
      }
    }
    A0a=A1a; A0b=A1b; A1a=A2a; A1b=A2b;
  }

  if constexpr (OUT_MODE==3){
    // th = (o @ W3) * ns
    #pragma unroll
    for (int r=0;r<4;r++){
      int row = row0 + wave*16 + (lane>>4)*4 + r;
      int sidx = row>=NN ? row-NN : row;
      float v = acc2[r]*ns2[sidx];
      size_t tof = row<NN ? (size_t)row*32 + c : (size_t)(row-NN)*32 + 16 + c;
      th[tof] = f2bf(v);
    }
    // discriminator dots: restage o_same / o_other rows into LDS (swizzled)
    __syncthreads();
    unsigned short* Os = &Bs[0];
    unsigned short* Oo = &Bs[8192];
    for (int p=t; p<2048; p+=256){
      int r = (p>>4)&63, seg = p&15;
      int row = row0 + r;
      int srcrow = (p<1024) ? row : (row<NN ? row+NN : row-NN);
      unsigned short* dst = (p<1024) ? Os : Oo;
      *(bf16x8*)&dst[r*128 + ((seg ^ (r&7))<<3)] = *(const bf16x8*)&A[(size_t)srcrow*128 + seg*8];
    }
    __syncthreads();
    float bb = scale[0];
    #pragma unroll
    for (int r=0;r<4;r++){
      int lr = wave*16 + (lane>>4)*4 + r;
      float dsame=0.f, doth=0.f;
      #pragma unroll
      for (int j=0;j<8;j++){
        float v = acc[j][r];
        int colj = j*16 + c;
        int idx = lr*128 + (((colj>>3) ^ (lr&7))<<3) + (colj&7);
        dsame += fmaxf(bf2f(Os[idx]),0.f)*v;
        doth  += fmaxf(bf2f(Oo[idx]),0.f)*v;
      }
      #pragma unroll
      for (int off=1; off<16; off<<=1){
        dsame += __shfl_xor(dsame, off);
        doth  += __shfl_xor(doth, off);
      }
      if (c==0){
        int row = row0 + lr;
        if (row < NN){
          ro[(size_t)row*2+0] = dsame + bb;
          ro[(size_t)row*2+1] = doth + bb;
        } else {
          int m = row - NN;
          roa[(size_t)m*2+0] = dsame + bb;
          roa[(size_t)m*2+1] = doth + bb;
        }
      }
    }
  } else {
    // C/D: col=lane&15, row=(lane>>4)*4+reg
    int rbase = row0 + wave*16 + (lane>>4)*4;
    #pragma unroll
    for (int j=0;j<8;j++){
      int colx = j*16 + c;
      #pragma unroll
      for (int r=0;r<4;r++){
        int row = rbase + r;
        if (row < nrows){
          float v = acc[j][r];
          if constexpr (OUT_MODE==0){
            out0[(size_t)row*256 + colx] = f2bf(v * scale[row]);
            int ir = inv[row];
            out0[(size_t)ir*256 + 128 + colx] = f2bf(v * scale[ir]);
          } else {
            int sidx = row >= NN ? row - NN : row;
            size_t zof = row < NN ? (size_t)row*256 + colx : (size_t)(row-NN)*256 + 128 + colx;
            out0[zof] = f2bf(v * scale[sidx]);
          }
        }
      }
    }
  }
}

// ---------------- CSR aggregation, width 128, interleaved z[N][2][128] ----------------
// wave per row; 2 edge-slots x 32 lanes (512B contiguous per edge);
// 1-iteration-ahead DATA prefetch: consume-oldest keeps next gathers in flight
template<bool RESID>
__global__ __launch_bounds__(256) void k_agg128(
  const unsigned short* __restrict__ z,
  const int* __restrict__ row_ptr, const int* __restrict__ col,
  const float* __restrict__ nd, const float* __restrict__ bias,
  unsigned short* __restrict__ ob, float* __restrict__ rn)
{
  int wave = threadIdx.x>>6, lane = threadIdx.x&63;
  int row = blockIdx.x*4 + wave;
  if (row >= NN) return;
  int s = row_ptr[row], e = row_ptr[row+1];
  int es = lane>>5;
  int half = (lane>>4)&1;
  int c8 = (lane&15)*8;
  size_t lof = (size_t)half*128 + c8;
  float acc[8] = {};
  int i = s + es;
  int sc0 = (i < e) ? col[i] : -1;
  int sc1 = (i+2 < e) ? col[i+2] : -1;
  bf16x8 u0 = {}, u1 = {};
  if (sc0 >= 0) u0 = *(const bf16x8*)(z + (size_t)sc0*256 + lof);
  if (sc1 >= 0) u1 = *(const bf16x8*)(z + (size_t)sc1*256 + lof);
  while (sc0 >= 0){
    int ni = i + 4;
    int nsc0 = (ni < e) ? col[ni] : -1;
    int nsc1 = (ni+2 < e) ? col[ni+2] : -1;
    bf16x8 v0 = {}, v1 = {};
    if (nsc0 >= 0) v0 = *(const bf16x8*)(z + (size_t)nsc0*256 + lof);
    if (nsc1 >= 0) v1 = *(const bf16x8*)(z + (size_t)nsc1*256 + lof);
    #pragma unroll
    for (int j=0;j<8;j++) acc[j] += bf2f((unsigned short)u0[j]);
    if (sc1 >= 0){
      #pragma unroll
      for (int j=0;j<8;j++) acc[j] += bf2f((unsigned short)u1[j]);
    }
    u0 = v0; u1 = v1; sc0 = nsc0; sc1 = nsc1; i = ni;
  }
  #pragma unroll
  for (int j=0;j<8;j++) acc[j] += __shfl_down(acc[j], 32);
  if (lane < 32){
    float ndr = nd[row];
    size_t oof = half ? (size_t)(NN+row)*128 + c8 : (size_t)row*128 + c8;
    float ra[8];
    #pragma unroll
    for (int j=0;j<8;j++) ra[j] = acc[j]*ndr + bias[c8+j];
    if constexpr (RESID){
      bf16x8 pv = *(const bf16x8*)(ob + oof);
      #pragma unroll
      for (int j=0;j<8;j++) ra[j] += bf2f((unsigned short)pv[j]);
    }
    bf16x8 wv;
    #pragma unroll
    for (int j=0;j<8;j++) wv[j] = (short)f2bf(ra[j]);
    *(bf16x8*)(ob + oof) = wv;
    if constexpr (RESID){
      float sa = 0.f;
      #pragma unroll
      for (int j=0;j<8;j++){ float x1 = fmaxf(ra[j],0.f); sa += x1*x1; }
      sa += __shfl_down(sa, 8);
      sa += __shfl_down(sa, 4);
      sa += __shfl_down(sa, 2);
      sa += __shfl_down(sa, 1);
      if ((lane&15)==0) rn[half ? NN+row : row] = 1.0f/fmaxf(sqrtf(sa),1e-12f);
    }
  }
}

// ---------------- width-16 aggregation (GC3), th[N][2][16], 8 edge-slots/wave ----------------
__global__ __launch_bounds__(256) void k_agg16(
  const unsigned short* __restrict__ th,
  const int* __restrict__ row_ptr, const int* __restrict__ col,
  const float* __restrict__ nd, const float* __restrict__ b3,
  float* __restrict__ hout, float* __restrict__ h2)
{
  int wave = threadIdx.x>>6, lane = threadIdx.x&63;
  int row = blockIdx.x*4 + wave;
  if (row >= NN) return;
  int s = row_ptr[row], e = row_ptr[row+1];
  int es = lane>>3, l8 = lane&7;
  float a4[4] = {};
  int i = s + es;
  int sc0 = (i<e)? col[i] : -1;
  int sc1 = (i+8<e)? col[i+8] : -1;
  bf16x4 u0 = {}, u1 = {};
  if (sc0 >= 0) u0 = *(const bf16x4*)(th + (size_t)sc0*32 + l8*4);
  if (sc1 >= 0) u1 = *(const bf16x4*)(th + (size_t)sc1*32 + l8*4);
  while (sc0 >= 0){
    int ni = i + 16;
    int nsc0 = (ni<e)? col[ni] : -1;
    int nsc1 = (ni+8<e)? col[ni+8] : -1;
    bf16x4 v0 = {}, v1 = {};
    if (nsc0 >= 0) v0 = *(const bf16x4*)(th + (size_t)nsc0*32 + l8*4);
    if (nsc1 >= 0) v1 = *(const bf16x4*)(th + (size_t)nsc1*32 + l8*4);
    #pragma unroll
    for (int j=0;j<4;j++) a4[j] += bf2f((unsigned short)u0[j]);
    if (sc1 >= 0){
      #pragma unroll
      for (int j=0;j<4;j++) a4[j] += bf2f((unsigned short)u1[j]);
    }
    u0 = v0; u1 = v1; sc0 = nsc0; sc1 = nsc1; i = ni;
  }
  #pragma unroll
  for (int j=0;j<4;j++){
    a4[j] += __shfl_down(a4[j], 32);
    a4[j] += __shfl_down(a4[j], 16);
    a4[j] += __shfl_down(a4[j], 8);
  }
  if (lane < 8){
    float ndr = nd[row];
    int half = l8>>2, c0 = (l8&3)*4;
    float4 r;
    r.x = a4[0]*ndr + b3[c0+0];
    r.y = a4[1]*ndr + b3[c0+1];
    r.z = a4[2]*ndr + b3[c0+2];
    r.w = a4[3]*ndr + b3[c0+3];
    if (half==0) *(float4*)&hout[(size_t)row*16 + c0] = r;
    else         *(float4*)&h2  [(size_t)row*16 + c0] = r;
  }
}

// ---------------- ret_h / ret_ha ----------------
__global__ __launch_bounds__(256) void k_ret_h(const float* __restrict__ h1, const float* __restrict__ h2,
  const float* __restrict__ Wdh, const float* __restrict__ bdh,
  float* __restrict__ rh, float* __restrict__ rha)
{
  __shared__ float Ws[256];
  int t = threadIdx.x;
  if (t<256) Ws[t]=Wdh[t];
  __syncthreads();
  int n = blockIdx.x*256 + t;
  if (n>=NN) return;
  float e1[16], e2[16];
  float s1=0.f, s2=0.f;
  const float* p1 = h1 + (size_t)n*16;
  const float* p2 = h2 + (size_t)n*16;
  #pragma unroll
  for (int i=0;i<16;i++){
    e1[i]=fmaxf(p1[i],0.f); s1+=e1[i]*e1[i];
    e2[i]=fmaxf(p2[i],0.f); s2+=e2[i]*e2[i];
  }
  float r1 = 1.0f/fmaxf(sqrtf(s1),1e-12f);
  float r2 = 1.0f/fmaxf(sqrtf(s2),1e-12f);
  float g1[16], g2[16];
  #pragma unroll
  for (int i=0;i<16;i++){ g1[i]=sigm(e1[i]*r1); g2[i]=sigm(e2[i]*r2); }
  float q00=0.f,q01=0.f,q10=0.f,q11=0.f;
  #pragma unroll
  for (int d=0; d<16; d++){
    float vh1=0.f, vh2=0.f;
    #pragma unroll
    for (int e=0;e<16;e++){ vh1 += Ws[d*16+e]*g1[e]; vh2 += Ws[d*16+e]*g2[e]; }
    q00 += e1[d]*vh1; q01 += e2[d]*vh1;
    q10 += e2[d]*vh2; q11 += e1[d]*vh2;
  }
  float bb = bdh[0];
  rh [(size_t)n*2+0]=q00+bb; rh [(size_t)n*2+1]=q01+bb;
  rha[(size_t)n*2+0]=q10+bb; rha[(size_t)n*2+1]=q11+bb;
}

// ---------------- launch ----------------
extern "C" void kernel_launch(void* const* d_in, const int* in_sizes, int n_in,
                              void* d_out, int out_size, void* d_ws, size_t ws_size,
                              hipStream_t stream){
  const float* x   = (const float*)d_in[0];
  const float* W1  = (const float*)d_in[1];
  const float* b1  = (const float*)d_in[2];
  const float* W2  = (const float*)d_in[3];
  const float* b2  = (const float*)d_in[4];
  const float* W3  = (const float*)d_in[5];
  const float* b3  = (const float*)d_in[6];
  const float* Wdo = (const float*)d_in[7];
  const float* bdo = (const float*)d_in[8];
  const float* Wdh = (const float*)d_in[9];
  const float* bdh = (const float*)d_in[10];
  const int* ei    = (const int*)d_in[11];
  const int* perm  = (const int*)d_in[12];
  const int* esrc = ei;
  const int* edst = ei + EE;

  char* ws = (char*)d_ws;
  size_t off = 0;
  auto alloc = [&](size_t bytes)->void*{ void* p = ws + off; off += (bytes + 255) & ~(size_t)255; return p; };
  unsigned short* z  = (unsigned short*)alloc((size_t)NN*256*2);   // messages interleaved [N][2][128]
  unsigned short* ob = (unsigned short*)alloc((size_t)2*NN*128*2); // o bf16: rows 0..NN-1 enc1, NN.. enc2
  unsigned short* th = (unsigned short*)alloc((size_t)NN*32*2);    // GC3 messages interleaved [N][2][16]
  float* h2 = (float*)alloc((size_t)NN*16*4);
  int* deg = (int*)alloc((size_t)2*NN*4);
  int* dout_ = deg; int* din_ = deg + NN;
  float* ns = (float*)alloc((size_t)NN*4);
  float* nd = (float*)alloc((size_t)NN*4);
  int* inv  = (int*)alloc((size_t)NN*4);
  float* rn = (float*)alloc((size_t)2*NN*4);
  int* cursor = (int*)alloc((size_t)NN*4);
  int* row_ptr = (int*)alloc((size_t)(NN+1)*4);
  int* colx = (int*)alloc((size_t)EE*4);
  int* chunk = (int*)alloc((size_t)NN*4);
  int* bsum = (int*)alloc((size_t)SCB*4);
  int* bpre = (int*)alloc((size_t)SCB*4);
  unsigned short* W1T = (unsigned short*)alloc((size_t)1024*128*2);
  unsigned short* W2T = (unsigned short*)alloc((size_t)128*128*2);
  unsigned short* WdoB = (unsigned short*)alloc((size_t)128*128*2);
  unsigned short* W3c = (unsigned short*)alloc((size_t)16*128*2);

  float* out_h   = (float*)d_out;
  float* out_ro  = out_h  + (size_t)NN*16;
  float* out_rh  = out_ro + (size_t)NN*2;
  float* out_roa = out_rh + (size_t)NN*2;
  float* out_rha = out_roa+ (size_t)NN*2;

  hipMemsetAsync(deg, 0, (size_t)2*NN*4, stream);
  k_deg_wcvt<<<EE/256 + 648, 256, 0, stream>>>(esrc, edst, dout_, din_,
                                               W1, W2, Wdo, W3, W1T, W2T, WdoB, W3c);
  k_scan1<<<SCB, 1024, 0, stream>>>(din_, chunk, bsum);
  k_scan2<<<1, 128, 0, stream>>>(bsum, bpre, row_ptr);
  k_scan3<<<(NN+255)/256, 256, 0, stream>>>(din_, chunk, bpre, dout_, perm, row_ptr, cursor, ns, nd, inv);
  k_fill<<<EE/256, 256, 0, stream>>>(esrc, edst, cursor, colx);

  int gb1 = (NN + 63)/64;
  int gb2 = (2*NN)/64;
  // GC1: z = x@W1 once; epilogue scatters both encodes into interleaved z
  k_gemmA<1024,0,0,float><<<gb1,256,0,stream>>>(x, W1T, z, ns, inv, nullptr, NN,
                                                nullptr, nullptr, nullptr, nullptr, nullptr);
  k_agg128<false><<<(NN+3)/4,256,0,stream>>>(z, row_ptr, colx, nd, b1, ob, nullptr);
  // GC2 fused over both encodes, +residual agg (fuses rn)
  k_gemmA<128,0,1,unsigned short><<<gb2,256,0,stream>>>(ob, W2T, z, ns, nullptr, nullptr, 2*NN,
                                                nullptr, nullptr, nullptr, nullptr, nullptr);
  k_agg128<true><<<(NN+3)/4,256,0,stream>>>(z, row_ptr, colx, nd, b2, ob, rn);
  // disc GEMM + fused GC3-mult (th) + fused ret_o epilogue
  k_gemmA<128,1,3,unsigned short><<<gb2,256,0,stream>>>(ob, WdoB, nullptr, bdo, nullptr, rn, 2*NN,
                                                out_ro, out_roa, W3c, ns, th);
  k_agg16<<<(NN+3)/4,256,0,stream>>>(th, row_ptr, colx, nd, b3, out_h, h2);
  k_ret_h<<<(NN+255)/256,256,0,stream>>>(out_h, h2, Wdh, bdh, out_rh, out_rha);
}